// Round 10
// baseline (507.568 us; speedup 1.0000x reference)
//
#include <hip/hip_runtime.h>
#include <hip/hip_fp16.h>
#include <math.h>

#define BB 4
#define CC 32
#define KK 4
#define SS 4
#define NN 65536

constexpr int NCOMP = 64;      // B*K*S
constexpr int SSTRIDE = 1088;  // stats: Sxx[0..1023], sx[1024..1055], w[1056]
// params per comp: X fp32 packed [0..575], z[576..607], c0[608],
//                  X fp16 packed-8 [612..931] (320 floats = 640 halves)
constexpr int PSTRIDE = 936;
constexpr float EPS_ = 1e-6f;
constexpr float COVREG_ = 1e-4f;
constexpr float LOG2PI_C = 1.8378770664093453f;

// fp32 packed-triangular row offsets (row i padded to 4*(i/4+1) floats)
__device__ constexpr int XOFF_[32] = {
    0,   4,   8,   12,  16,  24,  32,  40,  48,  60,  72,
    84,  96,  112, 128, 144, 160, 180, 200, 220, 240, 264,
    288, 312, 336, 364, 392, 420, 448, 480, 512, 544};

// fp16 packed rows, padded to 8*(i/8+1) halves; offsets in halves
__device__ constexpr int XOFF8_[32] = {
    0,   8,   16,  24,  32,  40,  48,  56,  64,  80,  96,
    112, 128, 144, 160, 176, 192, 216, 240, 264, 288, 312,
    336, 360, 384, 416, 448, 480, 512, 544, 576, 608};

// ---------------------------------------------------------------------------
// Kernel 1: per-block partial sufficient stats (unchanged).
// ---------------------------------------------------------------------------
template <bool ITER0, bool ATOMIC, int TILES>
__global__ __launch_bounds__(256, 1) void gmm_accum(
    const float* __restrict__ feat, const int* __restrict__ labels,
    const float* __restrict__ resp, float* __restrict__ outbuf) {
  __shared__ float fT[64 * 36];
  __shared__ float resp_lds[64 * 4];
  __shared__ int lab_lds[64];

  const int t = threadIdx.x;
  const int b = blockIdx.y;
  const int blk0 = blockIdx.x * (TILES * 64);

  const int wv = t >> 6;
  const int l = t & 63;
  const int sc = (t >> 4) & 3;
  const int p = t & 15;
  const int a0 = (p >> 2) * 8;
  const int b0 = (p & 3) * 8;

  float acc[8][8];
#pragma unroll
  for (int x = 0; x < 8; ++x)
#pragma unroll
    for (int y = 0; y < 8; ++y) acc[x][y] = 0.f;
  float sx[8] = {0, 0, 0, 0, 0, 0, 0, 0};
  float wacc = 0.f;

  const int cload = t >> 4;
  const int i4 = (t & 15) * 4;

  float4 pf0, pf1;
  float4 presp = make_float4(0, 0, 0, 0);
  int plab = 0;
  {
    const int n0 = blk0;
    pf0 = *(const float4*)(feat + ((size_t)b * CC + cload) * NN + n0 + i4);
    pf1 = *(const float4*)(feat + ((size_t)b * CC + cload + 16) * NN + n0 + i4);
    if (t < 64) {
      plab = labels[b * NN + n0 + t];
      if (!ITER0)
        presp = *(const float4*)(resp + ((size_t)b * NN + n0 + t) * 4);
    }
  }

  for (int tile = 0; tile < TILES; ++tile) {
    fT[(i4 + 0) * 36 + cload] = pf0.x;
    fT[(i4 + 1) * 36 + cload] = pf0.y;
    fT[(i4 + 2) * 36 + cload] = pf0.z;
    fT[(i4 + 3) * 36 + cload] = pf0.w;
    fT[(i4 + 0) * 36 + cload + 16] = pf1.x;
    fT[(i4 + 1) * 36 + cload + 16] = pf1.y;
    fT[(i4 + 2) * 36 + cload + 16] = pf1.z;
    fT[(i4 + 3) * 36 + cload + 16] = pf1.w;
    if (t < 64) {
      lab_lds[t] = plab;
      if (ITER0) {
        const int cmp = (blk0 + tile * 64 + t) & 3;
        resp_lds[t * 4 + 0] = (cmp == 0) ? 1.f : 0.f;
        resp_lds[t * 4 + 1] = (cmp == 1) ? 1.f : 0.f;
        resp_lds[t * 4 + 2] = (cmp == 2) ? 1.f : 0.f;
        resp_lds[t * 4 + 3] = (cmp == 3) ? 1.f : 0.f;
      } else {
        resp_lds[t * 4 + 0] = presp.x;
        resp_lds[t * 4 + 1] = presp.y;
        resp_lds[t * 4 + 2] = presp.z;
        resp_lds[t * 4 + 3] = presp.w;
      }
    }
    __syncthreads();
    if (tile < TILES - 1) {
      const int n0 = blk0 + (tile + 1) * 64;
      pf0 = *(const float4*)(feat + ((size_t)b * CC + cload) * NN + n0 + i4);
      pf1 =
          *(const float4*)(feat + ((size_t)b * CC + cload + 16) * NN + n0 + i4);
      if (t < 64) {
        plab = labels[b * NN + n0 + t];
        if (!ITER0)
          presp = *(const float4*)(resp + ((size_t)b * NN + n0 + t) * 4);
      }
    }

    unsigned long long m = __ballot(lab_lds[l] == wv);
    while (m) {
      const int i = __builtin_ctzll(m);
      m &= m - 1;
      const float rs = resp_lds[i * 4 + sc];
      const float4 ra0 = *(const float4*)&fT[i * 36 + a0];
      const float4 ra1 = *(const float4*)&fT[i * 36 + a0 + 4];
      const float4 rb0 = *(const float4*)&fT[i * 36 + b0];
      const float4 rb1 = *(const float4*)&fT[i * 36 + b0 + 4];
      const float ra[8] = {ra0.x, ra0.y, ra0.z, ra0.w,
                           ra1.x, ra1.y, ra1.z, ra1.w};
      const float rb[8] = {rb0.x, rb0.y, rb0.z, rb0.w,
                           rb1.x, rb1.y, rb1.z, rb1.w};
#pragma unroll
      for (int x = 0; x < 8; ++x) {
        const float v = rs * ra[x];
#pragma unroll
        for (int y = 0; y < 8; ++y) acc[x][y] = fmaf(v, rb[y], acc[x][y]);
      }
#pragma unroll
      for (int y = 0; y < 8; ++y) sx[y] = fmaf(rs, rb[y], sx[y]);
      wacc += rs;
    }
    __syncthreads();
  }

  if (ATOMIC) {
    float* sg = outbuf + ((size_t)(b * KK + wv) * SS + sc) * SSTRIDE;
#pragma unroll
    for (int x = 0; x < 8; ++x)
#pragma unroll
      for (int y = 0; y < 8; ++y)
        atomicAdd(sg + (a0 + x) * 32 + b0 + y, acc[x][y]);
    if (p < 4) {
#pragma unroll
      for (int y = 0; y < 8; ++y) atomicAdd(sg + 1024 + b0 + y, sx[y]);
    }
    if (p == 0) atomicAdd(sg + 1056, wacc);
  } else {
    const int nb = NN / (TILES * 64);
    float* sg = outbuf + ((size_t)(b * nb + blockIdx.x) * 16 + (wv * 4 + sc)) *
                             SSTRIDE;
#pragma unroll
    for (int x = 0; x < 8; ++x)
#pragma unroll
      for (int y = 0; y < 8; ++y) sg[(a0 + x) * 32 + b0 + y] = acc[x][y];
    if (p < 4) {
#pragma unroll
      for (int y = 0; y < 8; ++y) sg[1024 + b0 + y] = sx[y];
    }
    if (p == 0) sg[1056] = wacc;
  }
}

// ---------------------------------------------------------------------------
// Kernel 1b: reduce block-partials -> stats (unchanged).
// ---------------------------------------------------------------------------
__global__ __launch_bounds__(256) void gmm_reduce(const float* __restrict__ part,
                                                  float* __restrict__ stats,
                                                  int nb) {
  const int idx = blockIdx.x * 256 + threadIdx.x;
  if (idx >= NCOMP * 1057) return;
  const int comp = idx / 1057;
  const int cell = idx - comp * 1057;
  const int b = comp >> 4, cl = comp & 15;
  const float* src = part + ((size_t)(b * nb) * 16 + cl) * SSTRIDE + cell;
  const size_t stride = (size_t)16 * SSTRIDE;
  float s0 = 0.f, s1 = 0.f;
#pragma unroll 8
  for (int blk = 0; blk < nb; blk += 2) {
    s0 += src[(size_t)blk * stride];
    s1 += src[(size_t)(blk + 1) * stride];
  }
  stats[(size_t)comp * SSTRIDE + cell] = s0 + s1;
}

// ---------------------------------------------------------------------------
// Kernel 2: params.  Emits fp32 packed X, z, c0, and packed fp16 X (unchanged).
// ---------------------------------------------------------------------------
__global__ __launch_bounds__(64) void gmm_params(const float* __restrict__ stats,
                                                 float* __restrict__ params) {
  __shared__ float A[32 * 33];
  __shared__ float X[32 * 33];
  __shared__ float mu[32];

  const int t = threadIdx.x;
  const int comp = blockIdx.x;
  const float* sg = stats + (size_t)comp * SSTRIDE;

  const float w = sg[1056];
  const float invw = 1.f / (w + EPS_);
  if (t < 32) mu[t] = sg[1024 + t] * invw;
  __syncthreads();

  for (int idx = t; idx < 1024; idx += 64) {
    const int c = idx >> 5, d = idx & 31;
    float v = sg[idx] * invw - mu[c] * mu[d];
    if (c == d) v += COVREG_;
    A[c * 33 + d] = v;
  }
  __syncthreads();

  float ldet = 0.f;
  for (int j = 0; j < 32; ++j) {
    const float diag = A[j * 33 + j];
    ldet += logf(diag);
    const float ljj = sqrtf(diag);
    const float inv = 1.f / ljj;
    __syncthreads();
    if (t == 0) A[j * 33 + j] = ljj;
    if (t < 31 - j) A[(j + 1 + t) * 33 + j] *= inv;
    __syncthreads();
    if (t < 31 - j) {
      const int i = j + 1 + t;
      const float lij = A[i * 33 + j];
      for (int m = j + 1; m <= i; ++m) A[i * 33 + m] -= lij * A[m * 33 + j];
    }
    __syncthreads();
  }

  if (t < 32) {
    const int c = t;
    for (int i = c; i < 32; ++i) {
      float sum = (i == c) ? 1.f : 0.f;
      for (int m = c; m < i; ++m) sum -= A[i * 33 + m] * X[m * 33 + c];
      X[i * 33 + c] = sum / A[i * 33 + i];
    }
  }
  __syncthreads();

  float* pg = params + (size_t)comp * PSTRIDE;
  for (int i = 0; i < 32; ++i) {
    const int L4 = 4 * ((i >> 2) + 1);
    if (t < L4) pg[XOFF_[i] + t] = (t <= i) ? X[i * 33 + t] : 0.f;
  }
  // fp16 packed copy (8-half chunks per row)
  {
    __half* xh = (__half*)(pg + 612);
    for (int i = 0; i < 32; ++i) {
      const int nh = 8 * ((i >> 3) + 1);
      if (t < nh) {
        const float v = (t <= i) ? X[i * 33 + t] : 0.f;
        xh[XOFF8_[i] + t] = __float2half(v);
      }
    }
  }
  if (t < 32) {
    float z = 0.f;
    for (int j = 0; j <= t; ++j) z += X[t * 33 + j] * mu[j];
    pg[576 + t] = z;
  }
  if (t == 0) {
    const int sib = comp & ~3;
    float wsum = 0.f;
    for (int s2 = 0; s2 < 4; ++s2)
      wsum += stats[(size_t)(sib + s2) * SSTRIDE + 1056];
    const float pi = (w + EPS_) / (wsum + SS * EPS_);
    pg[608] = logf(pi) - 0.5f * (CC * LOG2PI_C + ldet);
  }
}

// ---------------------------------------------------------------------------
// Kernel 3a v3: E-step own-class, per-thread, fp16 X (unchanged from R9).
// ---------------------------------------------------------------------------
constexpr int SLOT2 = 368;

__global__ __launch_bounds__(256) void gmm_estep_own(
    const float* __restrict__ feat, const int* __restrict__ labels,
    const float* __restrict__ params, float* __restrict__ resp) {
  __shared__ float plds[16 * SLOT2];
  const int t = threadIdx.x;
  const int b = blockIdx.y;
  const int n = blockIdx.x * 256 + t;

  for (int comp = 0; comp < 16; ++comp) {
    const int k = comp >> 2, s = comp & 3;
    const float* src = params + (size_t)(b * 16 + comp) * PSTRIDE;
    float* dst = plds + (s * 4 + k) * SLOT2 + k * 4;
    for (int j = t; j < 353; j += 256) {
      float v;
      if (j < 320)
        v = src[612 + j];
      else if (j < 352)
        v = src[576 + (j - 320)];
      else
        v = src[608];
      dst[j] = v;
    }
  }

  float f[32];
#pragma unroll
  for (int c = 0; c < 32; ++c) f[c] = feat[((size_t)b * CC + c) * NN + n];
  const int lab = labels[b * NN + n];
  __syncthreads();

  float lp0 = 0.f, lp1 = 0.f, lp2 = 0.f, lp3 = 0.f;
#pragma unroll 1
  for (int s = 0; s < 4; ++s) {
    const float* Xp = plds + (s * 4 + lab) * SLOT2 + lab * 4;
    const __half* Xh = (const __half*)Xp;
    float q = 0.f;
#pragma unroll
    for (int i4g = 0; i4g < 8; ++i4g) {
      const float4 zv = *(const float4*)(Xp + 320 + 4 * i4g);
      const float zarr[4] = {zv.x, zv.y, zv.z, zv.w};
#pragma unroll
      for (int ii = 0; ii < 4; ++ii) {
        const int i = 4 * i4g + ii;
        float y = 0.f;
#pragma unroll
        for (int j8 = 0; j8 <= (i >> 3); ++j8) {
          const int4 ch = *(const int4*)(Xh + XOFF8_[i] + 8 * j8);
          const __half2 h0 = __builtin_bit_cast(__half2, ch.x);
          const __half2 h1 = __builtin_bit_cast(__half2, ch.y);
          const __half2 h2 = __builtin_bit_cast(__half2, ch.z);
          const __half2 h3 = __builtin_bit_cast(__half2, ch.w);
          y = fmaf(__low2float(h0), f[8 * j8 + 0], y);
          y = fmaf(__high2float(h0), f[8 * j8 + 1], y);
          y = fmaf(__low2float(h1), f[8 * j8 + 2], y);
          y = fmaf(__high2float(h1), f[8 * j8 + 3], y);
          y = fmaf(__low2float(h2), f[8 * j8 + 4], y);
          y = fmaf(__high2float(h2), f[8 * j8 + 5], y);
          y = fmaf(__low2float(h3), f[8 * j8 + 6], y);
          y = fmaf(__high2float(h3), f[8 * j8 + 7], y);
        }
        const float d = y - zarr[ii];
        q = fmaf(d, d, q);
      }
    }
    const float lp = Xp[352] - 0.5f * q;
    lp0 = (s == 0) ? lp : lp0;
    lp1 = (s == 1) ? lp : lp1;
    lp2 = (s == 2) ? lp : lp2;
    lp3 = (s == 3) ? lp : lp3;
  }
  const float m = fmaxf(fmaxf(lp0, lp1), fmaxf(lp2, lp3));
  const float e0 = expf(lp0 - m), e1 = expf(lp1 - m);
  const float e2 = expf(lp2 - m), e3 = expf(lp3 - m);
  const float inv = 1.f / (e0 + e1 + e2 + e3);
  *(float4*)(resp + ((size_t)b * NN + n) * 4) =
      make_float4(e0 * inv, e1 * inv, e2 * inv, e3 * inv);
}

// ---------------------------------------------------------------------------
// Kernel 3b v2: final E-step — R4 structure (LDS staging, online LSE,
// 2 elems/thread) with fp16 X + float4 z: LDS instrs/comp/pair 177 -> 89
// (R6 diagnosis: kernel is LDS-issue-bound at 92us of its 99us).
// Reads are wave-uniform (broadcast) -> no skew needed.  Slot 356 floats:
// Xh[0..319] (640 halves), z[320..351], c0[352]; LDS 39.4 -> 22.8 KB.
// ---------------------------------------------------------------------------
constexpr int FSLOT = 356;

__global__ __launch_bounds__(256, 2) void gmm_estep_final(
    const float* __restrict__ feat, const float* __restrict__ params,
    float* __restrict__ out) {
  __shared__ float plds[16 * FSLOT];
  const int t = threadIdx.x;
  const int b = blockIdx.y;
  const int n0 = blockIdx.x * 512 + t;

  for (int comp = 0; comp < 16; ++comp) {
    const float* src = params + (size_t)(b * 16 + comp) * PSTRIDE;
    float* dst = plds + comp * FSLOT;
    for (int j = t; j < 353; j += 256) {
      float v;
      if (j < 320)
        v = src[612 + j];
      else if (j < 352)
        v = src[576 + (j - 320)];
      else
        v = src[608];
      dst[j] = v;
    }
  }

  float f0[32], f1[32];
#pragma unroll
  for (int c = 0; c < 32; ++c) {
    f0[c] = feat[((size_t)b * CC + c) * NN + n0];
    f1[c] = feat[((size_t)b * CC + c) * NN + n0 + 256];
  }
  __syncthreads();

  float cA0 = 0, cA1 = 0, cA2 = 0, cA3 = 0;
  float cB0 = 0, cB1 = 0, cB2 = 0, cB3 = 0;

#pragma unroll 1
  for (int k = 0; k < 4; ++k) {
    float mA = -1e30f, sA = 0.f, mB = -1e30f, sB = 0.f;
#pragma unroll 1
    for (int s = 0; s < 4; ++s) {
      const float* Xp = plds + (k * 4 + s) * FSLOT;
      const __half* Xh = (const __half*)Xp;
      float qA = 0.f, qB = 0.f;
#pragma unroll
      for (int i4g = 0; i4g < 8; ++i4g) {
        const float4 zv = *(const float4*)(Xp + 320 + 4 * i4g);
        const float zarr[4] = {zv.x, zv.y, zv.z, zv.w};
#pragma unroll
        for (int ii = 0; ii < 4; ++ii) {
          const int i = 4 * i4g + ii;
          float yA = 0.f, yB = 0.f;
#pragma unroll
          for (int j8 = 0; j8 <= (i >> 3); ++j8) {
            const int4 ch = *(const int4*)(Xh + XOFF8_[i] + 8 * j8);
            const __half2 h0 = __builtin_bit_cast(__half2, ch.x);
            const __half2 h1 = __builtin_bit_cast(__half2, ch.y);
            const __half2 h2 = __builtin_bit_cast(__half2, ch.z);
            const __half2 h3 = __builtin_bit_cast(__half2, ch.w);
            const float x0 = __low2float(h0), x1 = __high2float(h0);
            const float x2 = __low2float(h1), x3 = __high2float(h1);
            const float x4 = __low2float(h2), x5 = __high2float(h2);
            const float x6 = __low2float(h3), x7 = __high2float(h3);
            yA = fmaf(x0, f0[8 * j8 + 0], yA);
            yA = fmaf(x1, f0[8 * j8 + 1], yA);
            yA = fmaf(x2, f0[8 * j8 + 2], yA);
            yA = fmaf(x3, f0[8 * j8 + 3], yA);
            yA = fmaf(x4, f0[8 * j8 + 4], yA);
            yA = fmaf(x5, f0[8 * j8 + 5], yA);
            yA = fmaf(x6, f0[8 * j8 + 6], yA);
            yA = fmaf(x7, f0[8 * j8 + 7], yA);
            yB = fmaf(x0, f1[8 * j8 + 0], yB);
            yB = fmaf(x1, f1[8 * j8 + 1], yB);
            yB = fmaf(x2, f1[8 * j8 + 2], yB);
            yB = fmaf(x3, f1[8 * j8 + 3], yB);
            yB = fmaf(x4, f1[8 * j8 + 4], yB);
            yB = fmaf(x5, f1[8 * j8 + 5], yB);
            yB = fmaf(x6, f1[8 * j8 + 6], yB);
            yB = fmaf(x7, f1[8 * j8 + 7], yB);
          }
          const float zi = zarr[ii];
          const float dA = yA - zi;
          qA = fmaf(dA, dA, qA);
          const float dB = yB - zi;
          qB = fmaf(dB, dB, qB);
        }
      }
      const float c0v = Xp[352];
      const float lA = c0v - 0.5f * qA;
      const float lB = c0v - 0.5f * qB;
      const float nmA = fmaxf(mA, lA);
      sA = sA * expf(mA - nmA) + expf(lA - nmA);
      mA = nmA;
      const float nmB = fmaxf(mB, lB);
      sB = sB * expf(mB - nmB) + expf(lB - nmB);
      mB = nmB;
    }
    const float cllA = mA + logf(sA);
    const float cllB = mB + logf(sB);
    cA0 = (k == 0) ? cllA : cA0;
    cA1 = (k == 1) ? cllA : cA1;
    cA2 = (k == 2) ? cllA : cA2;
    cA3 = (k == 3) ? cllA : cA3;
    cB0 = (k == 0) ? cllB : cB0;
    cB1 = (k == 1) ? cllB : cB1;
    cB2 = (k == 2) ? cllB : cB2;
    cB3 = (k == 3) ? cllB : cB3;
  }

  {
    const float m = fmaxf(fmaxf(cA0, cA1), fmaxf(cA2, cA3));
    const float e0 = expf(cA0 - m), e1 = expf(cA1 - m);
    const float e2 = expf(cA2 - m), e3 = expf(cA3 - m);
    const float inv = 1.f / (e0 + e1 + e2 + e3);
    out[((size_t)b * KK + 0) * NN + n0] = e0 * inv;
    out[((size_t)b * KK + 1) * NN + n0] = e1 * inv;
    out[((size_t)b * KK + 2) * NN + n0] = e2 * inv;
    out[((size_t)b * KK + 3) * NN + n0] = e3 * inv;
  }
  {
    const float m = fmaxf(fmaxf(cB0, cB1), fmaxf(cB2, cB3));
    const float e0 = expf(cB0 - m), e1 = expf(cB1 - m);
    const float e2 = expf(cB2 - m), e3 = expf(cB3 - m);
    const float inv = 1.f / (e0 + e1 + e2 + e3);
    out[((size_t)b * KK + 0) * NN + n0 + 256] = e0 * inv;
    out[((size_t)b * KK + 1) * NN + n0 + 256] = e1 * inv;
    out[((size_t)b * KK + 2) * NN + n0 + 256] = e2 * inv;
    out[((size_t)b * KK + 3) * NN + n0 + 256] = e3 * inv;
  }
}

// ---------------------------------------------------------------------------
extern "C" void kernel_launch(void* const* d_in, const int* in_sizes, int n_in,
                              void* d_out, int out_size, void* d_ws,
                              size_t ws_size, hipStream_t stream) {
  const float* feat = (const float*)d_in[0];
  const int* labels = (const int*)d_in[1];
  float* out = (float*)d_out;

  float* stats = (float*)d_ws;
  float* params = stats + (size_t)NCOMP * SSTRIDE;
  float* resp_ws = params + (size_t)NCOMP * PSTRIDE;
  float* partials = resp_ws + (size_t)BB * NN * 4;

  constexpr int NB = 128;
  const size_t resp_end_b =
      ((size_t)NCOMP * SSTRIDE + (size_t)NCOMP * PSTRIDE + (size_t)BB * NN * 4) *
      sizeof(float);
  const size_t part_end_b =
      resp_end_b + (size_t)BB * NB * 16 * SSTRIDE * sizeof(float);
  const bool have_resp = ws_size >= resp_end_b;
  const bool have_part = ws_size >= part_end_b;
  float* resp = have_resp ? resp_ws : out;

  const int reduce_blocks = (NCOMP * 1057 + 255) / 256;

  for (int it = 0; it < 3; ++it) {
    if (have_part) {
      if (it == 0)
        gmm_accum<true, false, 8>
            <<<dim3(NB, BB), 256, 0, stream>>>(feat, labels, resp, partials);
      else
        gmm_accum<false, false, 8>
            <<<dim3(NB, BB), 256, 0, stream>>>(feat, labels, resp, partials);
      gmm_reduce<<<reduce_blocks, 256, 0, stream>>>(partials, stats, NB);
    } else {
      hipMemsetAsync(stats, 0, (size_t)NCOMP * SSTRIDE * sizeof(float), stream);
      if (it == 0)
        gmm_accum<true, true, 16>
            <<<dim3(64, BB), 256, 0, stream>>>(feat, labels, resp, stats);
      else
        gmm_accum<false, true, 16>
            <<<dim3(64, BB), 256, 0, stream>>>(feat, labels, resp, stats);
    }
    gmm_params<<<NCOMP, 64, 0, stream>>>(stats, params);
    if (it < 2)
      gmm_estep_own<<<dim3(256, BB), 256, 0, stream>>>(feat, labels, params,
                                                       resp);
    else
      gmm_estep_final<<<dim3(128, BB), 256, 0, stream>>>(feat, params, out);
  }
}

// Round 12
// 471.996 us; speedup vs baseline: 1.0754x; 1.0754x over previous
//
#include <hip/hip_runtime.h>
#include <hip/hip_fp16.h>
#include <math.h>

#define BB 4
#define CC 32
#define KK 4
#define SS 4
#define NN 65536

constexpr int NCOMP = 64;      // B*K*S
constexpr int SSTRIDE = 1088;  // stats: Sxx[0..1023], sx[1024..1055], w[1056]
// params per comp: X fp32 packed [0..575], z[576..607], c0[608],
//                  X fp16 DENSE [32][32] at [612..1123] (1024 halves = 512 floats)
constexpr int PSTRIDE = 1128;  // 16B-aligned, no overlap (R11 bug: was 936)
constexpr float EPS_ = 1e-6f;
constexpr float COVREG_ = 1e-4f;
constexpr float LOG2PI_C = 1.8378770664093453f;

// fp32 packed-triangular row offsets (row i padded to 4*(i/4+1) floats)
__device__ constexpr int XOFF_[32] = {
    0,   4,   8,   12,  16,  24,  32,  40,  48,  60,  72,
    84,  96,  112, 128, 144, 160, 180, 200, 220, 240, 264,
    288, 312, 336, 364, 392, 420, 448, 480, 512, 544};

typedef _Float16 half8 __attribute__((ext_vector_type(8)));
typedef float floatx4 __attribute__((ext_vector_type(4)));

// ---------------------------------------------------------------------------
// Kernel 1: per-block partial sufficient stats (unchanged).
// ---------------------------------------------------------------------------
template <bool ITER0, bool ATOMIC, int TILES>
__global__ __launch_bounds__(256, 1) void gmm_accum(
    const float* __restrict__ feat, const int* __restrict__ labels,
    const float* __restrict__ resp, float* __restrict__ outbuf) {
  __shared__ float fT[64 * 36];
  __shared__ float resp_lds[64 * 4];
  __shared__ int lab_lds[64];

  const int t = threadIdx.x;
  const int b = blockIdx.y;
  const int blk0 = blockIdx.x * (TILES * 64);

  const int wv = t >> 6;
  const int l = t & 63;
  const int sc = (t >> 4) & 3;
  const int p = t & 15;
  const int a0 = (p >> 2) * 8;
  const int b0 = (p & 3) * 8;

  float acc[8][8];
#pragma unroll
  for (int x = 0; x < 8; ++x)
#pragma unroll
    for (int y = 0; y < 8; ++y) acc[x][y] = 0.f;
  float sx[8] = {0, 0, 0, 0, 0, 0, 0, 0};
  float wacc = 0.f;

  const int cload = t >> 4;
  const int i4 = (t & 15) * 4;

  float4 pf0, pf1;
  float4 presp = make_float4(0, 0, 0, 0);
  int plab = 0;
  {
    const int n0 = blk0;
    pf0 = *(const float4*)(feat + ((size_t)b * CC + cload) * NN + n0 + i4);
    pf1 = *(const float4*)(feat + ((size_t)b * CC + cload + 16) * NN + n0 + i4);
    if (t < 64) {
      plab = labels[b * NN + n0 + t];
      if (!ITER0)
        presp = *(const float4*)(resp + ((size_t)b * NN + n0 + t) * 4);
    }
  }

  for (int tile = 0; tile < TILES; ++tile) {
    fT[(i4 + 0) * 36 + cload] = pf0.x;
    fT[(i4 + 1) * 36 + cload] = pf0.y;
    fT[(i4 + 2) * 36 + cload] = pf0.z;
    fT[(i4 + 3) * 36 + cload] = pf0.w;
    fT[(i4 + 0) * 36 + cload + 16] = pf1.x;
    fT[(i4 + 1) * 36 + cload + 16] = pf1.y;
    fT[(i4 + 2) * 36 + cload + 16] = pf1.z;
    fT[(i4 + 3) * 36 + cload + 16] = pf1.w;
    if (t < 64) {
      lab_lds[t] = plab;
      if (ITER0) {
        const int cmp = (blk0 + tile * 64 + t) & 3;
        resp_lds[t * 4 + 0] = (cmp == 0) ? 1.f : 0.f;
        resp_lds[t * 4 + 1] = (cmp == 1) ? 1.f : 0.f;
        resp_lds[t * 4 + 2] = (cmp == 2) ? 1.f : 0.f;
        resp_lds[t * 4 + 3] = (cmp == 3) ? 1.f : 0.f;
      } else {
        resp_lds[t * 4 + 0] = presp.x;
        resp_lds[t * 4 + 1] = presp.y;
        resp_lds[t * 4 + 2] = presp.z;
        resp_lds[t * 4 + 3] = presp.w;
      }
    }
    __syncthreads();
    if (tile < TILES - 1) {
      const int n0 = blk0 + (tile + 1) * 64;
      pf0 = *(const float4*)(feat + ((size_t)b * CC + cload) * NN + n0 + i4);
      pf1 =
          *(const float4*)(feat + ((size_t)b * CC + cload + 16) * NN + n0 + i4);
      if (t < 64) {
        plab = labels[b * NN + n0 + t];
        if (!ITER0)
          presp = *(const float4*)(resp + ((size_t)b * NN + n0 + t) * 4);
      }
    }

    unsigned long long m = __ballot(lab_lds[l] == wv);
    while (m) {
      const int i = __builtin_ctzll(m);
      m &= m - 1;
      const float rs = resp_lds[i * 4 + sc];
      const float4 ra0 = *(const float4*)&fT[i * 36 + a0];
      const float4 ra1 = *(const float4*)&fT[i * 36 + a0 + 4];
      const float4 rb0 = *(const float4*)&fT[i * 36 + b0];
      const float4 rb1 = *(const float4*)&fT[i * 36 + b0 + 4];
      const float ra[8] = {ra0.x, ra0.y, ra0.z, ra0.w,
                           ra1.x, ra1.y, ra1.z, ra1.w};
      const float rb[8] = {rb0.x, rb0.y, rb0.z, rb0.w,
                           rb1.x, rb1.y, rb1.z, rb1.w};
#pragma unroll
      for (int x = 0; x < 8; ++x) {
        const float v = rs * ra[x];
#pragma unroll
        for (int y = 0; y < 8; ++y) acc[x][y] = fmaf(v, rb[y], acc[x][y]);
      }
#pragma unroll
      for (int y = 0; y < 8; ++y) sx[y] = fmaf(rs, rb[y], sx[y]);
      wacc += rs;
    }
    __syncthreads();
  }

  if (ATOMIC) {
    float* sg = outbuf + ((size_t)(b * KK + wv) * SS + sc) * SSTRIDE;
#pragma unroll
    for (int x = 0; x < 8; ++x)
#pragma unroll
      for (int y = 0; y < 8; ++y)
        atomicAdd(sg + (a0 + x) * 32 + b0 + y, acc[x][y]);
    if (p < 4) {
#pragma unroll
      for (int y = 0; y < 8; ++y) atomicAdd(sg + 1024 + b0 + y, sx[y]);
    }
    if (p == 0) atomicAdd(sg + 1056, wacc);
  } else {
    const int nb = NN / (TILES * 64);
    float* sg = outbuf + ((size_t)(b * nb + blockIdx.x) * 16 + (wv * 4 + sc)) *
                             SSTRIDE;
#pragma unroll
    for (int x = 0; x < 8; ++x)
#pragma unroll
      for (int y = 0; y < 8; ++y) sg[(a0 + x) * 32 + b0 + y] = acc[x][y];
    if (p < 4) {
#pragma unroll
      for (int y = 0; y < 8; ++y) sg[1024 + b0 + y] = sx[y];
    }
    if (p == 0) sg[1056] = wacc;
  }
}

// ---------------------------------------------------------------------------
// Kernel 1b: reduce block-partials -> stats (unchanged).
// ---------------------------------------------------------------------------
__global__ __launch_bounds__(256) void gmm_reduce(const float* __restrict__ part,
                                                  float* __restrict__ stats,
                                                  int nb) {
  const int idx = blockIdx.x * 256 + threadIdx.x;
  if (idx >= NCOMP * 1057) return;
  const int comp = idx / 1057;
  const int cell = idx - comp * 1057;
  const int b = comp >> 4, cl = comp & 15;
  const float* src = part + ((size_t)(b * nb) * 16 + cl) * SSTRIDE + cell;
  const size_t stride = (size_t)16 * SSTRIDE;
  float s0 = 0.f, s1 = 0.f;
#pragma unroll 8
  for (int blk = 0; blk < nb; blk += 2) {
    s0 += src[(size_t)blk * stride];
    s1 += src[(size_t)(blk + 1) * stride];
  }
  stats[(size_t)comp * SSTRIDE + cell] = s0 + s1;
}

// ---------------------------------------------------------------------------
// Kernel 2: params.  Emits fp32 packed X, z, c0, and DENSE fp16 X[32][32].
// ---------------------------------------------------------------------------
__global__ __launch_bounds__(64) void gmm_params(const float* __restrict__ stats,
                                                 float* __restrict__ params) {
  __shared__ float A[32 * 33];
  __shared__ float X[32 * 33];
  __shared__ float mu[32];

  const int t = threadIdx.x;
  const int comp = blockIdx.x;
  const float* sg = stats + (size_t)comp * SSTRIDE;

  const float w = sg[1056];
  const float invw = 1.f / (w + EPS_);
  if (t < 32) mu[t] = sg[1024 + t] * invw;
  __syncthreads();

  for (int idx = t; idx < 1024; idx += 64) {
    const int c = idx >> 5, d = idx & 31;
    float v = sg[idx] * invw - mu[c] * mu[d];
    if (c == d) v += COVREG_;
    A[c * 33 + d] = v;
  }
  __syncthreads();

  float ldet = 0.f;
  for (int j = 0; j < 32; ++j) {
    const float diag = A[j * 33 + j];
    ldet += logf(diag);
    const float ljj = sqrtf(diag);
    const float inv = 1.f / ljj;
    __syncthreads();
    if (t == 0) A[j * 33 + j] = ljj;
    if (t < 31 - j) A[(j + 1 + t) * 33 + j] *= inv;
    __syncthreads();
    if (t < 31 - j) {
      const int i = j + 1 + t;
      const float lij = A[i * 33 + j];
      for (int m = j + 1; m <= i; ++m) A[i * 33 + m] -= lij * A[m * 33 + j];
    }
    __syncthreads();
  }

  if (t < 32) {
    const int c = t;
    for (int i = c; i < 32; ++i) {
      float sum = (i == c) ? 1.f : 0.f;
      for (int m = c; m < i; ++m) sum -= A[i * 33 + m] * X[m * 33 + c];
      X[i * 33 + c] = sum / A[i * 33 + i];
    }
  }
  __syncthreads();

  float* pg = params + (size_t)comp * PSTRIDE;
  for (int i = 0; i < 32; ++i) {
    const int L4 = 4 * ((i >> 2) + 1);
    if (t < L4) pg[XOFF_[i] + t] = (t <= i) ? X[i * 33 + t] : 0.f;
  }
  // dense fp16 X[32][32] (zeros above diagonal): 1024 halves at pg[612..1123]
  {
    __half* xh = (__half*)(pg + 612);
    for (int i = 0; i < 32; ++i) {
      if (t < 32) {
        const float v = (t <= i) ? X[i * 33 + t] : 0.f;
        xh[i * 32 + t] = __float2half(v);
      }
    }
  }
  if (t < 32) {
    float z = 0.f;
    for (int j = 0; j <= t; ++j) z += X[t * 33 + j] * mu[j];
    pg[576 + t] = z;
  }
  if (t == 0) {
    const int sib = comp & ~3;
    float wsum = 0.f;
    for (int s2 = 0; s2 < 4; ++s2)
      wsum += stats[(size_t)(sib + s2) * SSTRIDE + 1056];
    const float pi = (w + EPS_) / (wsum + SS * EPS_);
    pg[608] = logf(pi) - 0.5f * (CC * LOG2PI_C + ldet);
  }
}

// ---------------------------------------------------------------------------
// Kernel 3a v4: E-step own-class via MFMA (mfma_f32_16x16x32_f16, K=32=C).
// A = dense fp16 X rows (32 frags = 16 comps x 2 row-tiles) in REGISTERS,
// loaded once, coalesced, statically indexed.  B = f-tile fragment from the
// fT staging (accum pattern), converted to fp16 in-register.  Per comp:
// 2 MFMAs -> d=y-z -> per-lane q -> shfl_xor(16,32) row-reduce -> label-
// masked softmax over the 4 own-class comps.
// D layout (m89-verified): col=lane&15, row=(lane>>4)*4+reg.
// A/B k-group mapping cancels (same fill order both operands).
// ---------------------------------------------------------------------------
__global__ __launch_bounds__(256, 2) void gmm_estep_own4(
    const float* __restrict__ feat, const int* __restrict__ labels,
    const float* __restrict__ params, float* __restrict__ resp) {
  __shared__ float fT[64 * 36];
  __shared__ float zlds[16 * 32];
  __shared__ float c0lds[16];
  __shared__ int lab_lds[64];

  const int t = threadIdx.x;
  const int b = blockIdx.y;
  const int blk0 = blockIdx.x * 256;  // 4 tiles of 64 elems
  const int w = t >> 6;
  const int l = t & 63;
  const int row16 = l & 15;   // A row within tile / B col (elem)
  const int kg = l >> 4;      // k-group: k = kg*8 + j

  // stage z and c0
  for (int idx = t; idx < 16 * 32; idx += 256) {
    zlds[idx] = params[(size_t)(b * 16 + (idx >> 5)) * PSTRIDE + 576 +
                       (idx & 31)];
  }
  if (t < 16) c0lds[t] = params[(size_t)(b * 16 + t) * PSTRIDE + 608];

  // preload all 32 A-fragments (16 comps x 2 row-tiles), statically indexed
  half8 afr[32];
#pragma unroll
  for (int tt = 0; tt < 32; ++tt) {
    const int c = tt >> 1, th = tt & 1;
    const _Float16* xb =
        (const _Float16*)(params + (size_t)(b * 16 + c) * PSTRIDE + 612);
    const int4 v =
        *(const int4*)(xb + (th * 16 + row16) * 32 + kg * 8);
    afr[tt] = __builtin_bit_cast(half8, v);
  }

  const int cload = t >> 4;
  const int i4 = (t & 15) * 4;
  const floatx4 zero4 = {0.f, 0.f, 0.f, 0.f};

  for (int tile = 0; tile < 4; ++tile) {
    const int base = blk0 + tile * 64;
    {
      const float4 v0 =
          *(const float4*)(feat + ((size_t)b * CC + cload) * NN + base + i4);
      const float4 v1 = *(const float4*)(feat +
                                         ((size_t)b * CC + cload + 16) * NN +
                                         base + i4);
      fT[(i4 + 0) * 36 + cload] = v0.x;
      fT[(i4 + 1) * 36 + cload] = v0.y;
      fT[(i4 + 2) * 36 + cload] = v0.z;
      fT[(i4 + 3) * 36 + cload] = v0.w;
      fT[(i4 + 0) * 36 + cload + 16] = v1.x;
      fT[(i4 + 1) * 36 + cload + 16] = v1.y;
      fT[(i4 + 2) * 36 + cload + 16] = v1.z;
      fT[(i4 + 3) * 36 + cload + 16] = v1.w;
      if (t < 64) lab_lds[t] = labels[b * NN + base + t];
    }
    __syncthreads();

    // B fragment: elem = w*16 + row16, k = kg*8 + j
    const int eoff = (w * 16 + row16) * 36 + kg * 8;
    const float4 fv0 = *(const float4*)&fT[eoff];
    const float4 fv1 = *(const float4*)&fT[eoff + 4];
    half8 bfr;
    bfr[0] = (_Float16)fv0.x;
    bfr[1] = (_Float16)fv0.y;
    bfr[2] = (_Float16)fv0.z;
    bfr[3] = (_Float16)fv0.w;
    bfr[4] = (_Float16)fv1.x;
    bfr[5] = (_Float16)fv1.y;
    bfr[6] = (_Float16)fv1.z;
    bfr[7] = (_Float16)fv1.w;

    const int lab = lab_lds[w * 16 + row16];

    float lp0 = 0.f, lp1 = 0.f, lp2 = 0.f, lp3 = 0.f;
#pragma unroll
    for (int c = 0; c < 16; ++c) {
      floatx4 y0 = __builtin_amdgcn_mfma_f32_16x16x32_f16(afr[2 * c], bfr,
                                                          zero4, 0, 0, 0);
      floatx4 y1 = __builtin_amdgcn_mfma_f32_16x16x32_f16(afr[2 * c + 1], bfr,
                                                          zero4, 0, 0, 0);
      const float4 zv0 = *(const float4*)&zlds[c * 32 + kg * 4];
      const float4 zv1 = *(const float4*)&zlds[c * 32 + 16 + kg * 4];
      float q = 0.f;
      {
        const float d0 = y0[0] - zv0.x;
        const float d1 = y0[1] - zv0.y;
        const float d2 = y0[2] - zv0.z;
        const float d3 = y0[3] - zv0.w;
        q = fmaf(d0, d0, q);
        q = fmaf(d1, d1, q);
        q = fmaf(d2, d2, q);
        q = fmaf(d3, d3, q);
        const float e0 = y1[0] - zv1.x;
        const float e1 = y1[1] - zv1.y;
        const float e2 = y1[2] - zv1.z;
        const float e3 = y1[3] - zv1.w;
        q = fmaf(e0, e0, q);
        q = fmaf(e1, e1, q);
        q = fmaf(e2, e2, q);
        q = fmaf(e3, e3, q);
      }
      // reduce over the 4 lane-groups (rows)
      q += __shfl_xor(q, 16);
      q += __shfl_xor(q, 32);
      const float lp = c0lds[c] - 0.5f * q;
      const bool own = (c >> 2) == lab;
      const int s = c & 3;
      lp0 = (own && s == 0) ? lp : lp0;
      lp1 = (own && s == 1) ? lp : lp1;
      lp2 = (own && s == 2) ? lp : lp2;
      lp3 = (own && s == 3) ? lp : lp3;
    }

    const float m = fmaxf(fmaxf(lp0, lp1), fmaxf(lp2, lp3));
    const float e0 = expf(lp0 - m), e1 = expf(lp1 - m);
    const float e2 = expf(lp2 - m), e3 = expf(lp3 - m);
    const float inv = 1.f / (e0 + e1 + e2 + e3);
    if (l < 16) {
      *(float4*)(resp + ((size_t)b * NN + base + w * 16 + l) * 4) =
          make_float4(e0 * inv, e1 * inv, e2 * inv, e3 * inv);
    }
    __syncthreads();
  }
}

// ---------------------------------------------------------------------------
// Kernel 3b: final E-step — R9-measured-best (fp32 X in LDS, online LSE,
// 2 elems/thread, 99us).  Local LDS stride 616.
// ---------------------------------------------------------------------------
__global__ __launch_bounds__(256, 2) void gmm_estep_final(
    const float* __restrict__ feat, const float* __restrict__ params,
    float* __restrict__ out) {
  __shared__ float plds[16 * 616];
  const int t = threadIdx.x;
  const int b = blockIdx.y;
  const int n0 = blockIdx.x * 512 + t;

  for (int comp = 0; comp < 16; ++comp) {
    const float* src = params + (size_t)(b * 16 + comp) * PSTRIDE;
    float* dst = plds + comp * 616;
    for (int j = t; j < 609; j += 256) dst[j] = src[j];
  }

  float f0[32], f1[32];
#pragma unroll
  for (int c = 0; c < 32; ++c) {
    f0[c] = feat[((size_t)b * CC + c) * NN + n0];
    f1[c] = feat[((size_t)b * CC + c) * NN + n0 + 256];
  }
  __syncthreads();

  float cA0 = 0, cA1 = 0, cA2 = 0, cA3 = 0;
  float cB0 = 0, cB1 = 0, cB2 = 0, cB3 = 0;

#pragma unroll 1
  for (int k = 0; k < 4; ++k) {
    float mA = -1e30f, sA = 0.f, mB = -1e30f, sB = 0.f;
#pragma unroll 1
    for (int s = 0; s < 4; ++s) {
      const float* Xp = plds + (k * 4 + s) * 616;
      float qA = 0.f, qB = 0.f;
#pragma unroll
      for (int i = 0; i < 32; ++i) {
        const int g = i >> 2;
        float yA = 0.f, yB = 0.f;
#pragma unroll
        for (int j4 = 0; j4 <= g; ++j4) {
          const float4 xv = *(const float4*)(Xp + XOFF_[i] + 4 * j4);
          yA = fmaf(xv.x, f0[4 * j4 + 0], yA);
          yA = fmaf(xv.y, f0[4 * j4 + 1], yA);
          yA = fmaf(xv.z, f0[4 * j4 + 2], yA);
          yA = fmaf(xv.w, f0[4 * j4 + 3], yA);
          yB = fmaf(xv.x, f1[4 * j4 + 0], yB);
          yB = fmaf(xv.y, f1[4 * j4 + 1], yB);
          yB = fmaf(xv.z, f1[4 * j4 + 2], yB);
          yB = fmaf(xv.w, f1[4 * j4 + 3], yB);
        }
        const float zi = Xp[576 + i];
        const float dA = yA - zi;
        qA = fmaf(dA, dA, qA);
        const float dB = yB - zi;
        qB = fmaf(dB, dB, qB);
      }
      const float c0v = Xp[608];
      const float lA = c0v - 0.5f * qA;
      const float lB = c0v - 0.5f * qB;
      const float nmA = fmaxf(mA, lA);
      sA = sA * expf(mA - nmA) + expf(lA - nmA);
      mA = nmA;
      const float nmB = fmaxf(mB, lB);
      sB = sB * expf(mB - nmB) + expf(lB - nmB);
      mB = nmB;
    }
    const float cllA = mA + logf(sA);
    const float cllB = mB + logf(sB);
    cA0 = (k == 0) ? cllA : cA0;
    cA1 = (k == 1) ? cllA : cA1;
    cA2 = (k == 2) ? cllA : cA2;
    cA3 = (k == 3) ? cllA : cA3;
    cB0 = (k == 0) ? cllB : cB0;
    cB1 = (k == 1) ? cllB : cB1;
    cB2 = (k == 2) ? cllB : cB2;
    cB3 = (k == 3) ? cllB : cB3;
  }

  {
    const float m = fmaxf(fmaxf(cA0, cA1), fmaxf(cA2, cA3));
    const float e0 = expf(cA0 - m), e1 = expf(cA1 - m);
    const float e2 = expf(cA2 - m), e3 = expf(cA3 - m);
    const float inv = 1.f / (e0 + e1 + e2 + e3);
    out[((size_t)b * KK + 0) * NN + n0] = e0 * inv;
    out[((size_t)b * KK + 1) * NN + n0] = e1 * inv;
    out[((size_t)b * KK + 2) * NN + n0] = e2 * inv;
    out[((size_t)b * KK + 3) * NN + n0] = e3 * inv;
  }
  {
    const float m = fmaxf(fmaxf(cB0, cB1), fmaxf(cB2, cB3));
    const float e0 = expf(cB0 - m), e1 = expf(cB1 - m);
    const float e2 = expf(cB2 - m), e3 = expf(cB3 - m);
    const float inv = 1.f / (e0 + e1 + e2 + e3);
    out[((size_t)b * KK + 0) * NN + n0 + 256] = e0 * inv;
    out[((size_t)b * KK + 1) * NN + n0 + 256] = e1 * inv;
    out[((size_t)b * KK + 2) * NN + n0 + 256] = e2 * inv;
    out[((size_t)b * KK + 3) * NN + n0 + 256] = e3 * inv;
  }
}

// ---------------------------------------------------------------------------
extern "C" void kernel_launch(void* const* d_in, const int* in_sizes, int n_in,
                              void* d_out, int out_size, void* d_ws,
                              size_t ws_size, hipStream_t stream) {
  const float* feat = (const float*)d_in[0];
  const int* labels = (const int*)d_in[1];
  float* out = (float*)d_out;

  float* stats = (float*)d_ws;
  float* params = stats + (size_t)NCOMP * SSTRIDE;
  float* resp_ws = params + (size_t)NCOMP * PSTRIDE;
  float* partials = resp_ws + (size_t)BB * NN * 4;

  constexpr int NB = 128;
  const size_t resp_end_b =
      ((size_t)NCOMP * SSTRIDE + (size_t)NCOMP * PSTRIDE + (size_t)BB * NN * 4) *
      sizeof(float);
  const size_t part_end_b =
      resp_end_b + (size_t)BB * NB * 16 * SSTRIDE * sizeof(float);
  const bool have_resp = ws_size >= resp_end_b;
  const bool have_part = ws_size >= part_end_b;
  float* resp = have_resp ? resp_ws : out;

  const int reduce_blocks = (NCOMP * 1057 + 255) / 256;

  for (int it = 0; it < 3; ++it) {
    if (have_part) {
      if (it == 0)
        gmm_accum<true, false, 8>
            <<<dim3(NB, BB), 256, 0, stream>>>(feat, labels, resp, partials);
      else
        gmm_accum<false, false, 8>
            <<<dim3(NB, BB), 256, 0, stream>>>(feat, labels, resp, partials);
      gmm_reduce<<<reduce_blocks, 256, 0, stream>>>(partials, stats, NB);
    } else {
      hipMemsetAsync(stats, 0, (size_t)NCOMP * SSTRIDE * sizeof(float), stream);
      if (it == 0)
        gmm_accum<true, true, 16>
            <<<dim3(64, BB), 256, 0, stream>>>(feat, labels, resp, stats);
      else
        gmm_accum<false, true, 16>
            <<<dim3(64, BB), 256, 0, stream>>>(feat, labels, resp, stats);
    }
    gmm_params<<<NCOMP, 64, 0, stream>>>(stats, params);
    if (it < 2)
      gmm_estep_own4<<<dim3(NN / 256, BB), 256, 0, stream>>>(feat, labels,
                                                             params, resp);
    else
      gmm_estep_final<<<dim3(128, BB), 256, 0, stream>>>(feat, params, out);
  }
}

// Round 13
// 471.321 us; speedup vs baseline: 1.0769x; 1.0014x over previous
//
#include <hip/hip_runtime.h>
#include <hip/hip_fp16.h>
#include <math.h>

#define BB 4
#define CC 32
#define KK 4
#define SS 4
#define NN 65536

constexpr int NCOMP = 64;      // B*K*S
constexpr int SSTRIDE = 1088;  // stats: Sxx[0..1023], sx[1024..1055], w[1056]
// params per comp: X fp32 packed [0..575], z[576..607], c0[608],
//   X fp16 FRAGMENT-MAJOR [612..1123]: xh[(th*64+l)*8+j] =
//     X[th*16+(l&15)][(l>>4)*8+j]  (1024 halves = 512 floats)
constexpr int PSTRIDE = 1128;
constexpr float EPS_ = 1e-6f;
constexpr float COVREG_ = 1e-4f;
constexpr float LOG2PI_C = 1.8378770664093453f;

// fp32 packed-triangular row offsets (row i padded to 4*(i/4+1) floats)
__device__ constexpr int XOFF_[32] = {
    0,   4,   8,   12,  16,  24,  32,  40,  48,  60,  72,
    84,  96,  112, 128, 144, 160, 180, 200, 220, 240, 264,
    288, 312, 336, 364, 392, 420, 448, 480, 512, 544};

typedef _Float16 half8 __attribute__((ext_vector_type(8)));
typedef float floatx4 __attribute__((ext_vector_type(4)));

// ---------------------------------------------------------------------------
// Kernel 1: per-block partial sufficient stats (unchanged).
// ---------------------------------------------------------------------------
template <bool ITER0, bool ATOMIC, int TILES>
__global__ __launch_bounds__(256, 1) void gmm_accum(
    const float* __restrict__ feat, const int* __restrict__ labels,
    const float* __restrict__ resp, float* __restrict__ outbuf) {
  __shared__ float fT[64 * 36];
  __shared__ float resp_lds[64 * 4];
  __shared__ int lab_lds[64];

  const int t = threadIdx.x;
  const int b = blockIdx.y;
  const int blk0 = blockIdx.x * (TILES * 64);

  const int wv = t >> 6;
  const int l = t & 63;
  const int sc = (t >> 4) & 3;
  const int p = t & 15;
  const int a0 = (p >> 2) * 8;
  const int b0 = (p & 3) * 8;

  float acc[8][8];
#pragma unroll
  for (int x = 0; x < 8; ++x)
#pragma unroll
    for (int y = 0; y < 8; ++y) acc[x][y] = 0.f;
  float sx[8] = {0, 0, 0, 0, 0, 0, 0, 0};
  float wacc = 0.f;

  const int cload = t >> 4;
  const int i4 = (t & 15) * 4;

  float4 pf0, pf1;
  float4 presp = make_float4(0, 0, 0, 0);
  int plab = 0;
  {
    const int n0 = blk0;
    pf0 = *(const float4*)(feat + ((size_t)b * CC + cload) * NN + n0 + i4);
    pf1 = *(const float4*)(feat + ((size_t)b * CC + cload + 16) * NN + n0 + i4);
    if (t < 64) {
      plab = labels[b * NN + n0 + t];
      if (!ITER0)
        presp = *(const float4*)(resp + ((size_t)b * NN + n0 + t) * 4);
    }
  }

  for (int tile = 0; tile < TILES; ++tile) {
    fT[(i4 + 0) * 36 + cload] = pf0.x;
    fT[(i4 + 1) * 36 + cload] = pf0.y;
    fT[(i4 + 2) * 36 + cload] = pf0.z;
    fT[(i4 + 3) * 36 + cload] = pf0.w;
    fT[(i4 + 0) * 36 + cload + 16] = pf1.x;
    fT[(i4 + 1) * 36 + cload + 16] = pf1.y;
    fT[(i4 + 2) * 36 + cload + 16] = pf1.z;
    fT[(i4 + 3) * 36 + cload + 16] = pf1.w;
    if (t < 64) {
      lab_lds[t] = plab;
      if (ITER0) {
        const int cmp = (blk0 + tile * 64 + t) & 3;
        resp_lds[t * 4 + 0] = (cmp == 0) ? 1.f : 0.f;
        resp_lds[t * 4 + 1] = (cmp == 1) ? 1.f : 0.f;
        resp_lds[t * 4 + 2] = (cmp == 2) ? 1.f : 0.f;
        resp_lds[t * 4 + 3] = (cmp == 3) ? 1.f : 0.f;
      } else {
        resp_lds[t * 4 + 0] = presp.x;
        resp_lds[t * 4 + 1] = presp.y;
        resp_lds[t * 4 + 2] = presp.z;
        resp_lds[t * 4 + 3] = presp.w;
      }
    }
    __syncthreads();
    if (tile < TILES - 1) {
      const int n0 = blk0 + (tile + 1) * 64;
      pf0 = *(const float4*)(feat + ((size_t)b * CC + cload) * NN + n0 + i4);
      pf1 =
          *(const float4*)(feat + ((size_t)b * CC + cload + 16) * NN + n0 + i4);
      if (t < 64) {
        plab = labels[b * NN + n0 + t];
        if (!ITER0)
          presp = *(const float4*)(resp + ((size_t)b * NN + n0 + t) * 4);
      }
    }

    unsigned long long m = __ballot(lab_lds[l] == wv);
    while (m) {
      const int i = __builtin_ctzll(m);
      m &= m - 1;
      const float rs = resp_lds[i * 4 + sc];
      const float4 ra0 = *(const float4*)&fT[i * 36 + a0];
      const float4 ra1 = *(const float4*)&fT[i * 36 + a0 + 4];
      const float4 rb0 = *(const float4*)&fT[i * 36 + b0];
      const float4 rb1 = *(const float4*)&fT[i * 36 + b0 + 4];
      const float ra[8] = {ra0.x, ra0.y, ra0.z, ra0.w,
                           ra1.x, ra1.y, ra1.z, ra1.w};
      const float rb[8] = {rb0.x, rb0.y, rb0.z, rb0.w,
                           rb1.x, rb1.y, rb1.z, rb1.w};
#pragma unroll
      for (int x = 0; x < 8; ++x) {
        const float v = rs * ra[x];
#pragma unroll
        for (int y = 0; y < 8; ++y) acc[x][y] = fmaf(v, rb[y], acc[x][y]);
      }
#pragma unroll
      for (int y = 0; y < 8; ++y) sx[y] = fmaf(rs, rb[y], sx[y]);
      wacc += rs;
    }
    __syncthreads();
  }

  if (ATOMIC) {
    float* sg = outbuf + ((size_t)(b * KK + wv) * SS + sc) * SSTRIDE;
#pragma unroll
    for (int x = 0; x < 8; ++x)
#pragma unroll
      for (int y = 0; y < 8; ++y)
        atomicAdd(sg + (a0 + x) * 32 + b0 + y, acc[x][y]);
    if (p < 4) {
#pragma unroll
      for (int y = 0; y < 8; ++y) atomicAdd(sg + 1024 + b0 + y, sx[y]);
    }
    if (p == 0) atomicAdd(sg + 1056, wacc);
  } else {
    const int nb = NN / (TILES * 64);
    float* sg = outbuf + ((size_t)(b * nb + blockIdx.x) * 16 + (wv * 4 + sc)) *
                             SSTRIDE;
#pragma unroll
    for (int x = 0; x < 8; ++x)
#pragma unroll
      for (int y = 0; y < 8; ++y) sg[(a0 + x) * 32 + b0 + y] = acc[x][y];
    if (p < 4) {
#pragma unroll
      for (int y = 0; y < 8; ++y) sg[1024 + b0 + y] = sx[y];
    }
    if (p == 0) sg[1056] = wacc;
  }
}

// ---------------------------------------------------------------------------
// Kernel 1b: reduce block-partials -> stats (unchanged).
// ---------------------------------------------------------------------------
__global__ __launch_bounds__(256) void gmm_reduce(const float* __restrict__ part,
                                                  float* __restrict__ stats,
                                                  int nb) {
  const int idx = blockIdx.x * 256 + threadIdx.x;
  if (idx >= NCOMP * 1057) return;
  const int comp = idx / 1057;
  const int cell = idx - comp * 1057;
  const int b = comp >> 4, cl = comp & 15;
  const float* src = part + ((size_t)(b * nb) * 16 + cl) * SSTRIDE + cell;
  const size_t stride = (size_t)16 * SSTRIDE;
  float s0 = 0.f, s1 = 0.f;
#pragma unroll 8
  for (int blk = 0; blk < nb; blk += 2) {
    s0 += src[(size_t)blk * stride];
    s1 += src[(size_t)(blk + 1) * stride];
  }
  stats[(size_t)comp * SSTRIDE + cell] = s0 + s1;
}

// ---------------------------------------------------------------------------
// Kernel 2: params.  Emits fp32 packed X, z, c0, and FRAGMENT-MAJOR fp16 X.
// ---------------------------------------------------------------------------
__global__ __launch_bounds__(64) void gmm_params(const float* __restrict__ stats,
                                                 float* __restrict__ params) {
  __shared__ float A[32 * 33];
  __shared__ float X[32 * 33];
  __shared__ float mu[32];

  const int t = threadIdx.x;
  const int comp = blockIdx.x;
  const float* sg = stats + (size_t)comp * SSTRIDE;

  const float w = sg[1056];
  const float invw = 1.f / (w + EPS_);
  if (t < 32) mu[t] = sg[1024 + t] * invw;
  __syncthreads();

  for (int idx = t; idx < 1024; idx += 64) {
    const int c = idx >> 5, d = idx & 31;
    float v = sg[idx] * invw - mu[c] * mu[d];
    if (c == d) v += COVREG_;
    A[c * 33 + d] = v;
  }
  __syncthreads();

  float ldet = 0.f;
  for (int j = 0; j < 32; ++j) {
    const float diag = A[j * 33 + j];
    ldet += logf(diag);
    const float ljj = sqrtf(diag);
    const float inv = 1.f / ljj;
    __syncthreads();
    if (t == 0) A[j * 33 + j] = ljj;
    if (t < 31 - j) A[(j + 1 + t) * 33 + j] *= inv;
    __syncthreads();
    if (t < 31 - j) {
      const int i = j + 1 + t;
      const float lij = A[i * 33 + j];
      for (int m = j + 1; m <= i; ++m) A[i * 33 + m] -= lij * A[m * 33 + j];
    }
    __syncthreads();
  }

  if (t < 32) {
    const int c = t;
    for (int i = c; i < 32; ++i) {
      float sum = (i == c) ? 1.f : 0.f;
      for (int m = c; m < i; ++m) sum -= A[i * 33 + m] * X[m * 33 + c];
      X[i * 33 + c] = sum / A[i * 33 + i];
    }
  }
  __syncthreads();

  float* pg = params + (size_t)comp * PSTRIDE;
  for (int i = 0; i < 32; ++i) {
    const int L4 = 4 * ((i >> 2) + 1);
    if (t < L4) pg[XOFF_[i] + t] = (t <= i) ? X[i * 33 + t] : 0.f;
  }
  // fragment-major fp16 X: lane slot l=t gets rows th*16+(t&15), k-chunk t>>4
  {
    __half* xh = (__half*)(pg + 612);
#pragma unroll
    for (int th = 0; th < 2; ++th) {
      const int row = th * 16 + (t & 15);
      const int k0 = (t >> 4) * 8;
#pragma unroll
      for (int j = 0; j < 8; ++j) {
        const int k = k0 + j;
        const float v = (k <= row) ? X[row * 33 + k] : 0.f;
        xh[(th * 64 + t) * 8 + j] = __float2half(v);
      }
    }
  }
  if (t < 32) {
    float z = 0.f;
    for (int j = 0; j <= t; ++j) z += X[t * 33 + j] * mu[j];
    pg[576 + t] = z;
  }
  if (t == 0) {
    const int sib = comp & ~3;
    float wsum = 0.f;
    for (int s2 = 0; s2 < 4; ++s2)
      wsum += stats[(size_t)(sib + s2) * SSTRIDE + 1056];
    const float pi = (w + EPS_) / (wsum + SS * EPS_);
    pg[608] = logf(pi) - 0.5f * (CC * LOG2PI_C + ldet);
  }
}

// ---------------------------------------------------------------------------
// Kernel 3a v5: E-step own-class via MFMA with LDS-resident fragment-major X.
// (R12 bug-class fix: afr[32] regs = 128 VGPR blew the lb(256,2) budget ->
// spill; now X lives in LDS, 32KB/block, and each A-fragment is ONE
// contiguous conflict-free ds_read_b128: lane l reads c*2048 + th*1024 + l*16.)
// ---------------------------------------------------------------------------
__global__ __launch_bounds__(256, 2) void gmm_estep_own4(
    const float* __restrict__ feat, const int* __restrict__ labels,
    const float* __restrict__ params, float* __restrict__ resp) {
  __shared__ float fT[64 * 36];
  __shared__ int4 xlds4[2048];  // 16 comps x 1024 halves = 32KB
  __shared__ float zlds[16 * 32];
  __shared__ float c0lds[16];
  __shared__ int lab_lds[64];

  const int t = threadIdx.x;
  const int b = blockIdx.y;
  const int blk0 = blockIdx.x * 256;
  const int w = t >> 6;
  const int l = t & 63;
  const int row16 = l & 15;
  const int kg = l >> 4;

  // stage fragment-major X (2048 int4, coalesced), z, c0
  for (int idx = t; idx < 2048; idx += 256) {
    const int c = idx >> 7, chunk = idx & 127;
    xlds4[idx] = *(const int4*)((const char*)(params +
                                              (size_t)(b * 16 + c) * PSTRIDE +
                                              612) +
                                chunk * 16);
  }
  for (int idx = t; idx < 16 * 32; idx += 256) {
    zlds[idx] =
        params[(size_t)(b * 16 + (idx >> 5)) * PSTRIDE + 576 + (idx & 31)];
  }
  if (t < 16) c0lds[t] = params[(size_t)(b * 16 + t) * PSTRIDE + 608];

  const _Float16* xl = (const _Float16*)xlds4;
  const int cload = t >> 4;
  const int i4 = (t & 15) * 4;
  const floatx4 zero4 = {0.f, 0.f, 0.f, 0.f};

  for (int tile = 0; tile < 4; ++tile) {
    const int base = blk0 + tile * 64;
    {
      const float4 v0 =
          *(const float4*)(feat + ((size_t)b * CC + cload) * NN + base + i4);
      const float4 v1 = *(const float4*)(feat +
                                         ((size_t)b * CC + cload + 16) * NN +
                                         base + i4);
      fT[(i4 + 0) * 36 + cload] = v0.x;
      fT[(i4 + 1) * 36 + cload] = v0.y;
      fT[(i4 + 2) * 36 + cload] = v0.z;
      fT[(i4 + 3) * 36 + cload] = v0.w;
      fT[(i4 + 0) * 36 + cload + 16] = v1.x;
      fT[(i4 + 1) * 36 + cload + 16] = v1.y;
      fT[(i4 + 2) * 36 + cload + 16] = v1.z;
      fT[(i4 + 3) * 36 + cload + 16] = v1.w;
      if (t < 64) lab_lds[t] = labels[b * NN + base + t];
    }
    __syncthreads();

    // B fragment: elem = w*16 + row16, k = kg*8 + j
    const int eoff = (w * 16 + row16) * 36 + kg * 8;
    const float4 fv0 = *(const float4*)&fT[eoff];
    const float4 fv1 = *(const float4*)&fT[eoff + 4];
    half8 bfr;
    bfr[0] = (_Float16)fv0.x;
    bfr[1] = (_Float16)fv0.y;
    bfr[2] = (_Float16)fv0.z;
    bfr[3] = (_Float16)fv0.w;
    bfr[4] = (_Float16)fv1.x;
    bfr[5] = (_Float16)fv1.y;
    bfr[6] = (_Float16)fv1.z;
    bfr[7] = (_Float16)fv1.w;

    const int lab = lab_lds[w * 16 + row16];

    float lp0 = 0.f, lp1 = 0.f, lp2 = 0.f, lp3 = 0.f;
#pragma unroll
    for (int c = 0; c < 16; ++c) {
      const half8 a0 = *(const half8*)&xl[c * 1024 + (0 * 64 + l) * 8];
      const half8 a1 = *(const half8*)&xl[c * 1024 + (1 * 64 + l) * 8];
      floatx4 y0 =
          __builtin_amdgcn_mfma_f32_16x16x32_f16(a0, bfr, zero4, 0, 0, 0);
      floatx4 y1 =
          __builtin_amdgcn_mfma_f32_16x16x32_f16(a1, bfr, zero4, 0, 0, 0);
      const float4 zv0 = *(const float4*)&zlds[c * 32 + kg * 4];
      const float4 zv1 = *(const float4*)&zlds[c * 32 + 16 + kg * 4];
      float q = 0.f;
      {
        const float d0 = y0[0] - zv0.x;
        const float d1 = y0[1] - zv0.y;
        const float d2 = y0[2] - zv0.z;
        const float d3 = y0[3] - zv0.w;
        q = fmaf(d0, d0, q);
        q = fmaf(d1, d1, q);
        q = fmaf(d2, d2, q);
        q = fmaf(d3, d3, q);
        const float e0 = y1[0] - zv1.x;
        const float e1 = y1[1] - zv1.y;
        const float e2 = y1[2] - zv1.z;
        const float e3 = y1[3] - zv1.w;
        q = fmaf(e0, e0, q);
        q = fmaf(e1, e1, q);
        q = fmaf(e2, e2, q);
        q = fmaf(e3, e3, q);
      }
      q += __shfl_xor(q, 16);
      q += __shfl_xor(q, 32);
      const float lp = c0lds[c] - 0.5f * q;
      const bool own = (c >> 2) == lab;
      const int s = c & 3;
      lp0 = (own && s == 0) ? lp : lp0;
      lp1 = (own && s == 1) ? lp : lp1;
      lp2 = (own && s == 2) ? lp : lp2;
      lp3 = (own && s == 3) ? lp : lp3;
    }

    const float m = fmaxf(fmaxf(lp0, lp1), fmaxf(lp2, lp3));
    const float e0 = expf(lp0 - m), e1 = expf(lp1 - m);
    const float e2 = expf(lp2 - m), e3 = expf(lp3 - m);
    const float inv = 1.f / (e0 + e1 + e2 + e3);
    if (l < 16) {
      *(float4*)(resp + ((size_t)b * NN + base + w * 16 + l) * 4) =
          make_float4(e0 * inv, e1 * inv, e2 * inv, e3 * inv);
    }
    __syncthreads();
  }
}

// ---------------------------------------------------------------------------
// Kernel 3b: final E-step — R9-measured-best (fp32 X in LDS, online LSE,
// 2 elems/thread, 99us).  Local LDS stride 616.
// ---------------------------------------------------------------------------
__global__ __launch_bounds__(256, 2) void gmm_estep_final(
    const float* __restrict__ feat, const float* __restrict__ params,
    float* __restrict__ out) {
  __shared__ float plds[16 * 616];
  const int t = threadIdx.x;
  const int b = blockIdx.y;
  const int n0 = blockIdx.x * 512 + t;

  for (int comp = 0; comp < 16; ++comp) {
    const float* src = params + (size_t)(b * 16 + comp) * PSTRIDE;
    float* dst = plds + comp * 616;
    for (int j = t; j < 609; j += 256) dst[j] = src[j];
  }

  float f0[32], f1[32];
#pragma unroll
  for (int c = 0; c < 32; ++c) {
    f0[c] = feat[((size_t)b * CC + c) * NN + n0];
    f1[c] = feat[((size_t)b * CC + c) * NN + n0 + 256];
  }
  __syncthreads();

  float cA0 = 0, cA1 = 0, cA2 = 0, cA3 = 0;
  float cB0 = 0, cB1 = 0, cB2 = 0, cB3 = 0;

#pragma unroll 1
  for (int k = 0; k < 4; ++k) {
    float mA = -1e30f, sA = 0.f, mB = -1e30f, sB = 0.f;
#pragma unroll 1
    for (int s = 0; s < 4; ++s) {
      const float* Xp = plds + (k * 4 + s) * 616;
      float qA = 0.f, qB = 0.f;
#pragma unroll
      for (int i = 0; i < 32; ++i) {
        const int g = i >> 2;
        float yA = 0.f, yB = 0.f;
#pragma unroll
        for (int j4 = 0; j4 <= g; ++j4) {
          const float4 xv = *(const float4*)(Xp + XOFF_[i] + 4 * j4);
          yA = fmaf(xv.x, f0[4 * j4 + 0], yA);
          yA = fmaf(xv.y, f0[4 * j4 + 1], yA);
          yA = fmaf(xv.z, f0[4 * j4 + 2], yA);
          yA = fmaf(xv.w, f0[4 * j4 + 3], yA);
          yB = fmaf(xv.x, f1[4 * j4 + 0], yB);
          yB = fmaf(xv.y, f1[4 * j4 + 1], yB);
          yB = fmaf(xv.z, f1[4 * j4 + 2], yB);
          yB = fmaf(xv.w, f1[4 * j4 + 3], yB);
        }
        const float zi = Xp[576 + i];
        const float dA = yA - zi;
        qA = fmaf(dA, dA, qA);
        const float dB = yB - zi;
        qB = fmaf(dB, dB, qB);
      }
      const float c0v = Xp[608];
      const float lA = c0v - 0.5f * qA;
      const float lB = c0v - 0.5f * qB;
      const float nmA = fmaxf(mA, lA);
      sA = sA * expf(mA - nmA) + expf(lA - nmA);
      mA = nmA;
      const float nmB = fmaxf(mB, lB);
      sB = sB * expf(mB - nmB) + expf(lB - nmB);
      mB = nmB;
    }
    const float cllA = mA + logf(sA);
    const float cllB = mB + logf(sB);
    cA0 = (k == 0) ? cllA : cA0;
    cA1 = (k == 1) ? cllA : cA1;
    cA2 = (k == 2) ? cllA : cA2;
    cA3 = (k == 3) ? cllA : cA3;
    cB0 = (k == 0) ? cllB : cB0;
    cB1 = (k == 1) ? cllB : cB1;
    cB2 = (k == 2) ? cllB : cB2;
    cB3 = (k == 3) ? cllB : cB3;
  }

  {
    const float m = fmaxf(fmaxf(cA0, cA1), fmaxf(cA2, cA3));
    const float e0 = expf(cA0 - m), e1 = expf(cA1 - m);
    const float e2 = expf(cA2 - m), e3 = expf(cA3 - m);
    const float inv = 1.f / (e0 + e1 + e2 + e3);
    out[((size_t)b * KK + 0) * NN + n0] = e0 * inv;
    out[((size_t)b * KK + 1) * NN + n0] = e1 * inv;
    out[((size_t)b * KK + 2) * NN + n0] = e2 * inv;
    out[((size_t)b * KK + 3) * NN + n0] = e3 * inv;
  }
  {
    const float m = fmaxf(fmaxf(cB0, cB1), fmaxf(cB2, cB3));
    const float e0 = expf(cB0 - m), e1 = expf(cB1 - m);
    const float e2 = expf(cB2 - m), e3 = expf(cB3 - m);
    const float inv = 1.f / (e0 + e1 + e2 + e3);
    out[((size_t)b * KK + 0) * NN + n0 + 256] = e0 * inv;
    out[((size_t)b * KK + 1) * NN + n0 + 256] = e1 * inv;
    out[((size_t)b * KK + 2) * NN + n0 + 256] = e2 * inv;
    out[((size_t)b * KK + 3) * NN + n0 + 256] = e3 * inv;
  }
}

// ---------------------------------------------------------------------------
extern "C" void kernel_launch(void* const* d_in, const int* in_sizes, int n_in,
                              void* d_out, int out_size, void* d_ws,
                              size_t ws_size, hipStream_t stream) {
  const float* feat = (const float*)d_in[0];
  const int* labels = (const int*)d_in[1];
  float* out = (float*)d_out;

  float* stats = (float*)d_ws;
  float* params = stats + (size_t)NCOMP * SSTRIDE;
  float* resp_ws = params + (size_t)NCOMP * PSTRIDE;
  float* partials = resp_ws + (size_t)BB * NN * 4;

  constexpr int NB = 128;
  const size_t resp_end_b =
      ((size_t)NCOMP * SSTRIDE + (size_t)NCOMP * PSTRIDE + (size_t)BB * NN * 4) *
      sizeof(float);
  const size_t part_end_b =
      resp_end_b + (size_t)BB * NB * 16 * SSTRIDE * sizeof(float);
  const bool have_resp = ws_size >= resp_end_b;
  const bool have_part = ws_size >= part_end_b;
  float* resp = have_resp ? resp_ws : out;

  const int reduce_blocks = (NCOMP * 1057 + 255) / 256;

  for (int it = 0; it < 3; ++it) {
    if (have_part) {
      if (it == 0)
        gmm_accum<true, false, 8>
            <<<dim3(NB, BB), 256, 0, stream>>>(feat, labels, resp, partials);
      else
        gmm_accum<false, false, 8>
            <<<dim3(NB, BB), 256, 0, stream>>>(feat, labels, resp, partials);
      gmm_reduce<<<reduce_blocks, 256, 0, stream>>>(partials, stats, NB);
    } else {
      hipMemsetAsync(stats, 0, (size_t)NCOMP * SSTRIDE * sizeof(float), stream);
      if (it == 0)
        gmm_accum<true, true, 16>
            <<<dim3(64, BB), 256, 0, stream>>>(feat, labels, resp, stats);
      else
        gmm_accum<false, true, 16>
            <<<dim3(64, BB), 256, 0, stream>>>(feat, labels, resp, stats);
    }
    gmm_params<<<NCOMP, 64, 0, stream>>>(stats, params);
    if (it < 2)
      gmm_estep_own4<<<dim3(NN / 256, BB), 256, 0, stream>>>(feat, labels,
                                                             params, resp);
    else
      gmm_estep_final<<<dim3(128, BB), 256, 0, stream>>>(feat, params, out);
  }
}

// Round 14
// 410.417 us; speedup vs baseline: 1.2367x; 1.1484x over previous
//
#include <hip/hip_runtime.h>
#include <hip/hip_fp16.h>
#include <math.h>

#define BB 4
#define CC 32
#define KK 4
#define SS 4
#define NN 65536

constexpr int NCOMP = 64;      // B*K*S
constexpr int SSTRIDE = 1088;  // stats: Sxx[0..1023], sx[1024..1055], w[1056]
// params per comp: X fp32 packed [0..575], z[576..607], c0[608],
//   X fp16 FRAGMENT-MAJOR [612..1123]: xh[(th*64+l)*8+j] =
//     X[th*16+(l&15)][(l>>4)*8+j]  (1024 halves = 512 floats)
constexpr int PSTRIDE = 1128;
constexpr float EPS_ = 1e-6f;
constexpr float COVREG_ = 1e-4f;
constexpr float LOG2PI_C = 1.8378770664093453f;

// fp32 packed-triangular row offsets (row i padded to 4*(i/4+1) floats)
__device__ constexpr int XOFF_[32] = {
    0,   4,   8,   12,  16,  24,  32,  40,  48,  60,  72,
    84,  96,  112, 128, 144, 160, 180, 200, 220, 240, 264,
    288, 312, 336, 364, 392, 420, 448, 480, 512, 544};

typedef _Float16 half8 __attribute__((ext_vector_type(8)));
typedef float floatx4 __attribute__((ext_vector_type(4)));

// ---------------------------------------------------------------------------
// Kernel 1: per-block partial sufficient stats (unchanged).
// ---------------------------------------------------------------------------
template <bool ITER0, bool ATOMIC, int TILES>
__global__ __launch_bounds__(256, 1) void gmm_accum(
    const float* __restrict__ feat, const int* __restrict__ labels,
    const float* __restrict__ resp, float* __restrict__ outbuf) {
  __shared__ float fT[64 * 36];
  __shared__ float resp_lds[64 * 4];
  __shared__ int lab_lds[64];

  const int t = threadIdx.x;
  const int b = blockIdx.y;
  const int blk0 = blockIdx.x * (TILES * 64);

  const int wv = t >> 6;
  const int l = t & 63;
  const int sc = (t >> 4) & 3;
  const int p = t & 15;
  const int a0 = (p >> 2) * 8;
  const int b0 = (p & 3) * 8;

  float acc[8][8];
#pragma unroll
  for (int x = 0; x < 8; ++x)
#pragma unroll
    for (int y = 0; y < 8; ++y) acc[x][y] = 0.f;
  float sx[8] = {0, 0, 0, 0, 0, 0, 0, 0};
  float wacc = 0.f;

  const int cload = t >> 4;
  const int i4 = (t & 15) * 4;

  float4 pf0, pf1;
  float4 presp = make_float4(0, 0, 0, 0);
  int plab = 0;
  {
    const int n0 = blk0;
    pf0 = *(const float4*)(feat + ((size_t)b * CC + cload) * NN + n0 + i4);
    pf1 = *(const float4*)(feat + ((size_t)b * CC + cload + 16) * NN + n0 + i4);
    if (t < 64) {
      plab = labels[b * NN + n0 + t];
      if (!ITER0)
        presp = *(const float4*)(resp + ((size_t)b * NN + n0 + t) * 4);
    }
  }

  for (int tile = 0; tile < TILES; ++tile) {
    fT[(i4 + 0) * 36 + cload] = pf0.x;
    fT[(i4 + 1) * 36 + cload] = pf0.y;
    fT[(i4 + 2) * 36 + cload] = pf0.z;
    fT[(i4 + 3) * 36 + cload] = pf0.w;
    fT[(i4 + 0) * 36 + cload + 16] = pf1.x;
    fT[(i4 + 1) * 36 + cload + 16] = pf1.y;
    fT[(i4 + 2) * 36 + cload + 16] = pf1.z;
    fT[(i4 + 3) * 36 + cload + 16] = pf1.w;
    if (t < 64) {
      lab_lds[t] = plab;
      if (ITER0) {
        const int cmp = (blk0 + tile * 64 + t) & 3;
        resp_lds[t * 4 + 0] = (cmp == 0) ? 1.f : 0.f;
        resp_lds[t * 4 + 1] = (cmp == 1) ? 1.f : 0.f;
        resp_lds[t * 4 + 2] = (cmp == 2) ? 1.f : 0.f;
        resp_lds[t * 4 + 3] = (cmp == 3) ? 1.f : 0.f;
      } else {
        resp_lds[t * 4 + 0] = presp.x;
        resp_lds[t * 4 + 1] = presp.y;
        resp_lds[t * 4 + 2] = presp.z;
        resp_lds[t * 4 + 3] = presp.w;
      }
    }
    __syncthreads();
    if (tile < TILES - 1) {
      const int n0 = blk0 + (tile + 1) * 64;
      pf0 = *(const float4*)(feat + ((size_t)b * CC + cload) * NN + n0 + i4);
      pf1 =
          *(const float4*)(feat + ((size_t)b * CC + cload + 16) * NN + n0 + i4);
      if (t < 64) {
        plab = labels[b * NN + n0 + t];
        if (!ITER0)
          presp = *(const float4*)(resp + ((size_t)b * NN + n0 + t) * 4);
      }
    }

    unsigned long long m = __ballot(lab_lds[l] == wv);
    while (m) {
      const int i = __builtin_ctzll(m);
      m &= m - 1;
      const float rs = resp_lds[i * 4 + sc];
      const float4 ra0 = *(const float4*)&fT[i * 36 + a0];
      const float4 ra1 = *(const float4*)&fT[i * 36 + a0 + 4];
      const float4 rb0 = *(const float4*)&fT[i * 36 + b0];
      const float4 rb1 = *(const float4*)&fT[i * 36 + b0 + 4];
      const float ra[8] = {ra0.x, ra0.y, ra0.z, ra0.w,
                           ra1.x, ra1.y, ra1.z, ra1.w};
      const float rb[8] = {rb0.x, rb0.y, rb0.z, rb0.w,
                           rb1.x, rb1.y, rb1.z, rb1.w};
#pragma unroll
      for (int x = 0; x < 8; ++x) {
        const float v = rs * ra[x];
#pragma unroll
        for (int y = 0; y < 8; ++y) acc[x][y] = fmaf(v, rb[y], acc[x][y]);
      }
#pragma unroll
      for (int y = 0; y < 8; ++y) sx[y] = fmaf(rs, rb[y], sx[y]);
      wacc += rs;
    }
    __syncthreads();
  }

  if (ATOMIC) {
    float* sg = outbuf + ((size_t)(b * KK + wv) * SS + sc) * SSTRIDE;
#pragma unroll
    for (int x = 0; x < 8; ++x)
#pragma unroll
      for (int y = 0; y < 8; ++y)
        atomicAdd(sg + (a0 + x) * 32 + b0 + y, acc[x][y]);
    if (p < 4) {
#pragma unroll
      for (int y = 0; y < 8; ++y) atomicAdd(sg + 1024 + b0 + y, sx[y]);
    }
    if (p == 0) atomicAdd(sg + 1056, wacc);
  } else {
    const int nb = NN / (TILES * 64);
    float* sg = outbuf + ((size_t)(b * nb + blockIdx.x) * 16 + (wv * 4 + sc)) *
                             SSTRIDE;
#pragma unroll
    for (int x = 0; x < 8; ++x)
#pragma unroll
      for (int y = 0; y < 8; ++y) sg[(a0 + x) * 32 + b0 + y] = acc[x][y];
    if (p < 4) {
#pragma unroll
      for (int y = 0; y < 8; ++y) sg[1024 + b0 + y] = sx[y];
    }
    if (p == 0) sg[1056] = wacc;
  }
}

// ---------------------------------------------------------------------------
// Kernel 1b: reduce block-partials -> stats (unchanged).
// ---------------------------------------------------------------------------
__global__ __launch_bounds__(256) void gmm_reduce(const float* __restrict__ part,
                                                  float* __restrict__ stats,
                                                  int nb) {
  const int idx = blockIdx.x * 256 + threadIdx.x;
  if (idx >= NCOMP * 1057) return;
  const int comp = idx / 1057;
  const int cell = idx - comp * 1057;
  const int b = comp >> 4, cl = comp & 15;
  const float* src = part + ((size_t)(b * nb) * 16 + cl) * SSTRIDE + cell;
  const size_t stride = (size_t)16 * SSTRIDE;
  float s0 = 0.f, s1 = 0.f;
#pragma unroll 8
  for (int blk = 0; blk < nb; blk += 2) {
    s0 += src[(size_t)blk * stride];
    s1 += src[(size_t)(blk + 1) * stride];
  }
  stats[(size_t)comp * SSTRIDE + cell] = s0 + s1;
}

// ---------------------------------------------------------------------------
// Kernel 2: params (unchanged from R13).
// ---------------------------------------------------------------------------
__global__ __launch_bounds__(64) void gmm_params(const float* __restrict__ stats,
                                                 float* __restrict__ params) {
  __shared__ float A[32 * 33];
  __shared__ float X[32 * 33];
  __shared__ float mu[32];

  const int t = threadIdx.x;
  const int comp = blockIdx.x;
  const float* sg = stats + (size_t)comp * SSTRIDE;

  const float w = sg[1056];
  const float invw = 1.f / (w + EPS_);
  if (t < 32) mu[t] = sg[1024 + t] * invw;
  __syncthreads();

  for (int idx = t; idx < 1024; idx += 64) {
    const int c = idx >> 5, d = idx & 31;
    float v = sg[idx] * invw - mu[c] * mu[d];
    if (c == d) v += COVREG_;
    A[c * 33 + d] = v;
  }
  __syncthreads();

  float ldet = 0.f;
  for (int j = 0; j < 32; ++j) {
    const float diag = A[j * 33 + j];
    ldet += logf(diag);
    const float ljj = sqrtf(diag);
    const float inv = 1.f / ljj;
    __syncthreads();
    if (t == 0) A[j * 33 + j] = ljj;
    if (t < 31 - j) A[(j + 1 + t) * 33 + j] *= inv;
    __syncthreads();
    if (t < 31 - j) {
      const int i = j + 1 + t;
      const float lij = A[i * 33 + j];
      for (int m = j + 1; m <= i; ++m) A[i * 33 + m] -= lij * A[m * 33 + j];
    }
    __syncthreads();
  }

  if (t < 32) {
    const int c = t;
    for (int i = c; i < 32; ++i) {
      float sum = (i == c) ? 1.f : 0.f;
      for (int m = c; m < i; ++m) sum -= A[i * 33 + m] * X[m * 33 + c];
      X[i * 33 + c] = sum / A[i * 33 + i];
    }
  }
  __syncthreads();

  float* pg = params + (size_t)comp * PSTRIDE;
  for (int i = 0; i < 32; ++i) {
    const int L4 = 4 * ((i >> 2) + 1);
    if (t < L4) pg[XOFF_[i] + t] = (t <= i) ? X[i * 33 + t] : 0.f;
  }
  // fragment-major fp16 X
  {
    __half* xh = (__half*)(pg + 612);
#pragma unroll
    for (int th = 0; th < 2; ++th) {
      const int row = th * 16 + (t & 15);
      const int k0 = (t >> 4) * 8;
#pragma unroll
      for (int j = 0; j < 8; ++j) {
        const int k = k0 + j;
        const float v = (k <= row) ? X[row * 33 + k] : 0.f;
        xh[(th * 64 + t) * 8 + j] = __float2half(v);
      }
    }
  }
  if (t < 32) {
    float z = 0.f;
    for (int j = 0; j <= t; ++j) z += X[t * 33 + j] * mu[j];
    pg[576 + t] = z;
  }
  if (t == 0) {
    const int sib = comp & ~3;
    float wsum = 0.f;
    for (int s2 = 0; s2 < 4; ++s2)
      wsum += stats[(size_t)(sib + s2) * SSTRIDE + 1056];
    const float pi = (w + EPS_) / (wsum + SS * EPS_);
    pg[608] = logf(pi) - 0.5f * (CC * LOG2PI_C + ldet);
  }
}

// ---------------------------------------------------------------------------
// Shared MFMA q-core: computes q[16 comps] for this wave's 16 elems.
// fT staged [64][36]; X fragment-major in xlds4; z in zlds; lane l: elem
// = wbase+(l&15), kg = l>>4.  After 2 shfl_xor, every lane holds full q.
// ---------------------------------------------------------------------------

// Kernel 3a v5: own-class E-step, MFMA core, TILES tiles of 64 elems.
template <int TILES>
__global__ __launch_bounds__(256, 2) void gmm_estep_own4(
    const float* __restrict__ feat, const int* __restrict__ labels,
    const float* __restrict__ params, float* __restrict__ resp) {
  __shared__ float fT[64 * 36];
  __shared__ int4 xlds4[2048];  // 16 comps x 1024 halves = 32KB
  __shared__ float zlds[16 * 32];
  __shared__ float c0lds[16];
  __shared__ int lab_lds[64];

  const int t = threadIdx.x;
  const int b = blockIdx.y;
  const int blk0 = blockIdx.x * (TILES * 64);
  const int w = t >> 6;
  const int l = t & 63;
  const int row16 = l & 15;
  const int kg = l >> 4;

  for (int idx = t; idx < 2048; idx += 256) {
    const int c = idx >> 7, chunk = idx & 127;
    xlds4[idx] = *(const int4*)((const char*)(params +
                                              (size_t)(b * 16 + c) * PSTRIDE +
                                              612) +
                                chunk * 16);
  }
  for (int idx = t; idx < 16 * 32; idx += 256) {
    zlds[idx] =
        params[(size_t)(b * 16 + (idx >> 5)) * PSTRIDE + 576 + (idx & 31)];
  }
  if (t < 16) c0lds[t] = params[(size_t)(b * 16 + t) * PSTRIDE + 608];

  const _Float16* xl = (const _Float16*)xlds4;
  const int cload = t >> 4;
  const int i4 = (t & 15) * 4;
  const floatx4 zero4 = {0.f, 0.f, 0.f, 0.f};

  for (int tile = 0; tile < TILES; ++tile) {
    const int base = blk0 + tile * 64;
    {
      const float4 v0 =
          *(const float4*)(feat + ((size_t)b * CC + cload) * NN + base + i4);
      const float4 v1 = *(const float4*)(feat +
                                         ((size_t)b * CC + cload + 16) * NN +
                                         base + i4);
      fT[(i4 + 0) * 36 + cload] = v0.x;
      fT[(i4 + 1) * 36 + cload] = v0.y;
      fT[(i4 + 2) * 36 + cload] = v0.z;
      fT[(i4 + 3) * 36 + cload] = v0.w;
      fT[(i4 + 0) * 36 + cload + 16] = v1.x;
      fT[(i4 + 1) * 36 + cload + 16] = v1.y;
      fT[(i4 + 2) * 36 + cload + 16] = v1.z;
      fT[(i4 + 3) * 36 + cload + 16] = v1.w;
      if (t < 64) lab_lds[t] = labels[b * NN + base + t];
    }
    __syncthreads();

    const int eoff = (w * 16 + row16) * 36 + kg * 8;
    const float4 fv0 = *(const float4*)&fT[eoff];
    const float4 fv1 = *(const float4*)&fT[eoff + 4];
    half8 bfr;
    bfr[0] = (_Float16)fv0.x;
    bfr[1] = (_Float16)fv0.y;
    bfr[2] = (_Float16)fv0.z;
    bfr[3] = (_Float16)fv0.w;
    bfr[4] = (_Float16)fv1.x;
    bfr[5] = (_Float16)fv1.y;
    bfr[6] = (_Float16)fv1.z;
    bfr[7] = (_Float16)fv1.w;

    const int lab = lab_lds[w * 16 + row16];

    float lp0 = 0.f, lp1 = 0.f, lp2 = 0.f, lp3 = 0.f;
#pragma unroll
    for (int c = 0; c < 16; ++c) {
      const half8 a0 = *(const half8*)&xl[c * 1024 + (0 * 64 + l) * 8];
      const half8 a1 = *(const half8*)&xl[c * 1024 + (1 * 64 + l) * 8];
      floatx4 y0 =
          __builtin_amdgcn_mfma_f32_16x16x32_f16(a0, bfr, zero4, 0, 0, 0);
      floatx4 y1 =
          __builtin_amdgcn_mfma_f32_16x16x32_f16(a1, bfr, zero4, 0, 0, 0);
      const float4 zv0 = *(const float4*)&zlds[c * 32 + kg * 4];
      const float4 zv1 = *(const float4*)&zlds[c * 32 + 16 + kg * 4];
      float q = 0.f;
      {
        const float d0 = y0[0] - zv0.x;
        const float d1 = y0[1] - zv0.y;
        const float d2 = y0[2] - zv0.z;
        const float d3 = y0[3] - zv0.w;
        q = fmaf(d0, d0, q);
        q = fmaf(d1, d1, q);
        q = fmaf(d2, d2, q);
        q = fmaf(d3, d3, q);
        const float e0 = y1[0] - zv1.x;
        const float e1 = y1[1] - zv1.y;
        const float e2 = y1[2] - zv1.z;
        const float e3 = y1[3] - zv1.w;
        q = fmaf(e0, e0, q);
        q = fmaf(e1, e1, q);
        q = fmaf(e2, e2, q);
        q = fmaf(e3, e3, q);
      }
      q += __shfl_xor(q, 16);
      q += __shfl_xor(q, 32);
      const float lp = c0lds[c] - 0.5f * q;
      const bool own = (c >> 2) == lab;
      const int s = c & 3;
      lp0 = (own && s == 0) ? lp : lp0;
      lp1 = (own && s == 1) ? lp : lp1;
      lp2 = (own && s == 2) ? lp : lp2;
      lp3 = (own && s == 3) ? lp : lp3;
    }

    const float m = fmaxf(fmaxf(lp0, lp1), fmaxf(lp2, lp3));
    const float e0 = expf(lp0 - m), e1 = expf(lp1 - m);
    const float e2 = expf(lp2 - m), e3 = expf(lp3 - m);
    const float inv = 1.f / (e0 + e1 + e2 + e3);
    if (l < 16) {
      *(float4*)(resp + ((size_t)b * NN + base + w * 16 + l) * 4) =
          make_float4(e0 * inv, e1 * inv, e2 * inv, e3 * inv);
    }
    __syncthreads();
  }
}

// ---------------------------------------------------------------------------
// Kernel 3b v3: final E-step via the SAME validated MFMA core.
// All 16 comps -> lp[16] (static regs) -> per-class flat LSE over s ->
// softmax over K -> out[B][K][N].  fp16-X accuracy in final pre-validated
// by R10 (absmax 3.9e-3).  No labels.
// ---------------------------------------------------------------------------
template <int TILES>
__global__ __launch_bounds__(256, 2) void gmm_estep_final4(
    const float* __restrict__ feat, const float* __restrict__ params,
    float* __restrict__ out) {
  __shared__ float fT[64 * 36];
  __shared__ int4 xlds4[2048];
  __shared__ float zlds[16 * 32];
  __shared__ float c0lds[16];

  const int t = threadIdx.x;
  const int b = blockIdx.y;
  const int blk0 = blockIdx.x * (TILES * 64);
  const int w = t >> 6;
  const int l = t & 63;
  const int row16 = l & 15;
  const int kg = l >> 4;

  for (int idx = t; idx < 2048; idx += 256) {
    const int c = idx >> 7, chunk = idx & 127;
    xlds4[idx] = *(const int4*)((const char*)(params +
                                              (size_t)(b * 16 + c) * PSTRIDE +
                                              612) +
                                chunk * 16);
  }
  for (int idx = t; idx < 16 * 32; idx += 256) {
    zlds[idx] =
        params[(size_t)(b * 16 + (idx >> 5)) * PSTRIDE + 576 + (idx & 31)];
  }
  if (t < 16) c0lds[t] = params[(size_t)(b * 16 + t) * PSTRIDE + 608];

  const _Float16* xl = (const _Float16*)xlds4;
  const int cload = t >> 4;
  const int i4 = (t & 15) * 4;
  const floatx4 zero4 = {0.f, 0.f, 0.f, 0.f};

  for (int tile = 0; tile < TILES; ++tile) {
    const int base = blk0 + tile * 64;
    {
      const float4 v0 =
          *(const float4*)(feat + ((size_t)b * CC + cload) * NN + base + i4);
      const float4 v1 = *(const float4*)(feat +
                                         ((size_t)b * CC + cload + 16) * NN +
                                         base + i4);
      fT[(i4 + 0) * 36 + cload] = v0.x;
      fT[(i4 + 1) * 36 + cload] = v0.y;
      fT[(i4 + 2) * 36 + cload] = v0.z;
      fT[(i4 + 3) * 36 + cload] = v0.w;
      fT[(i4 + 0) * 36 + cload + 16] = v1.x;
      fT[(i4 + 1) * 36 + cload + 16] = v1.y;
      fT[(i4 + 2) * 36 + cload + 16] = v1.z;
      fT[(i4 + 3) * 36 + cload + 16] = v1.w;
    }
    __syncthreads();

    const int eoff = (w * 16 + row16) * 36 + kg * 8;
    const float4 fv0 = *(const float4*)&fT[eoff];
    const float4 fv1 = *(const float4*)&fT[eoff + 4];
    half8 bfr;
    bfr[0] = (_Float16)fv0.x;
    bfr[1] = (_Float16)fv0.y;
    bfr[2] = (_Float16)fv0.z;
    bfr[3] = (_Float16)fv0.w;
    bfr[4] = (_Float16)fv1.x;
    bfr[5] = (_Float16)fv1.y;
    bfr[6] = (_Float16)fv1.z;
    bfr[7] = (_Float16)fv1.w;

    float lp[16];
#pragma unroll
    for (int c = 0; c < 16; ++c) {
      const half8 a0 = *(const half8*)&xl[c * 1024 + (0 * 64 + l) * 8];
      const half8 a1 = *(const half8*)&xl[c * 1024 + (1 * 64 + l) * 8];
      floatx4 y0 =
          __builtin_amdgcn_mfma_f32_16x16x32_f16(a0, bfr, zero4, 0, 0, 0);
      floatx4 y1 =
          __builtin_amdgcn_mfma_f32_16x16x32_f16(a1, bfr, zero4, 0, 0, 0);
      const float4 zv0 = *(const float4*)&zlds[c * 32 + kg * 4];
      const float4 zv1 = *(const float4*)&zlds[c * 32 + 16 + kg * 4];
      float q = 0.f;
      {
        const float d0 = y0[0] - zv0.x;
        const float d1 = y0[1] - zv0.y;
        const float d2 = y0[2] - zv0.z;
        const float d3 = y0[3] - zv0.w;
        q = fmaf(d0, d0, q);
        q = fmaf(d1, d1, q);
        q = fmaf(d2, d2, q);
        q = fmaf(d3, d3, q);
        const float e0 = y1[0] - zv1.x;
        const float e1 = y1[1] - zv1.y;
        const float e2 = y1[2] - zv1.z;
        const float e3 = y1[3] - zv1.w;
        q = fmaf(e0, e0, q);
        q = fmaf(e1, e1, q);
        q = fmaf(e2, e2, q);
        q = fmaf(e3, e3, q);
      }
      q += __shfl_xor(q, 16);
      q += __shfl_xor(q, 32);
      lp[c] = c0lds[c] - 0.5f * q;
    }

    // per-class flat LSE over s, then softmax over classes
    float cll[4];
#pragma unroll
    for (int k = 0; k < 4; ++k) {
      const float m = fmaxf(fmaxf(lp[4 * k + 0], lp[4 * k + 1]),
                            fmaxf(lp[4 * k + 2], lp[4 * k + 3]));
      const float s = expf(lp[4 * k + 0] - m) + expf(lp[4 * k + 1] - m) +
                      expf(lp[4 * k + 2] - m) + expf(lp[4 * k + 3] - m);
      cll[k] = m + logf(s);
    }
    const float m = fmaxf(fmaxf(cll[0], cll[1]), fmaxf(cll[2], cll[3]));
    const float e0 = expf(cll[0] - m), e1 = expf(cll[1] - m);
    const float e2 = expf(cll[2] - m), e3 = expf(cll[3] - m);
    const float inv = 1.f / (e0 + e1 + e2 + e3);
    if (l < 16) {
      const int n = base + w * 16 + l;
      out[((size_t)b * KK + 0) * NN + n] = e0 * inv;
      out[((size_t)b * KK + 1) * NN + n] = e1 * inv;
      out[((size_t)b * KK + 2) * NN + n] = e2 * inv;
      out[((size_t)b * KK + 3) * NN + n] = e3 * inv;
    }
    __syncthreads();
  }
}

// ---------------------------------------------------------------------------
extern "C" void kernel_launch(void* const* d_in, const int* in_sizes, int n_in,
                              void* d_out, int out_size, void* d_ws,
                              size_t ws_size, hipStream_t stream) {
  const float* feat = (const float*)d_in[0];
  const int* labels = (const int*)d_in[1];
  float* out = (float*)d_out;

  float* stats = (float*)d_ws;
  float* params = stats + (size_t)NCOMP * SSTRIDE;
  float* resp_ws = params + (size_t)NCOMP * PSTRIDE;
  float* partials = resp_ws + (size_t)BB * NN * 4;

  constexpr int NB = 128;
  const size_t resp_end_b =
      ((size_t)NCOMP * SSTRIDE + (size_t)NCOMP * PSTRIDE + (size_t)BB * NN * 4) *
      sizeof(float);
  const size_t part_end_b =
      resp_end_b + (size_t)BB * NB * 16 * SSTRIDE * sizeof(float);
  const bool have_resp = ws_size >= resp_end_b;
  const bool have_part = ws_size >= part_end_b;
  float* resp = have_resp ? resp_ws : out;

  const int reduce_blocks = (NCOMP * 1057 + 255) / 256;

  for (int it = 0; it < 3; ++it) {
    if (have_part) {
      if (it == 0)
        gmm_accum<true, false, 8>
            <<<dim3(NB, BB), 256, 0, stream>>>(feat, labels, resp, partials);
      else
        gmm_accum<false, false, 8>
            <<<dim3(NB, BB), 256, 0, stream>>>(feat, labels, resp, partials);
      gmm_reduce<<<reduce_blocks, 256, 0, stream>>>(partials, stats, NB);
    } else {
      hipMemsetAsync(stats, 0, (size_t)NCOMP * SSTRIDE * sizeof(float), stream);
      if (it == 0)
        gmm_accum<true, true, 16>
            <<<dim3(64, BB), 256, 0, stream>>>(feat, labels, resp, stats);
      else
        gmm_accum<false, true, 16>
            <<<dim3(64, BB), 256, 0, stream>>>(feat, labels, resp, stats);
    }
    gmm_params<<<NCOMP, 64, 0, stream>>>(stats, params);
    if (it < 2)
      gmm_estep_own4<8><<<dim3(NN / 512, BB), 256, 0, stream>>>(feat, labels,
                                                                params, resp);
    else
      gmm_estep_final4<8><<<dim3(NN / 512, BB), 256, 0, stream>>>(feat, params,
                                                                  out);
  }
}

// Round 15
// 341.451 us; speedup vs baseline: 1.4865x; 1.2020x over previous
//
#include <hip/hip_runtime.h>
#include <hip/hip_fp16.h>
#include <math.h>

#define BB 4
#define CC 32
#define KK 4
#define SS 4
#define NN 65536

constexpr int NCOMP = 64;      // B*K*S
constexpr int SSTRIDE = 1088;  // stats: Sxx[0..1023], sx[1024..1055], w[1056]
// params per comp: X fp32 packed [0..575], z[576..607], c0[608],
//   X fp16 FRAGMENT-MAJOR [612..1123]: xh[(th*64+l)*8+j] =
//     X[th*16+(l&15)][(l>>4)*8+j]  (1024 halves = 512 floats)
constexpr int PSTRIDE = 1128;
constexpr float EPS_ = 1e-6f;
constexpr float COVREG_ = 1e-4f;
constexpr float LOG2PI_C = 1.8378770664093453f;

// fp32 packed-triangular row offsets (row i padded to 4*(i/4+1) floats)
__device__ constexpr int XOFF_[32] = {
    0,   4,   8,   12,  16,  24,  32,  40,  48,  60,  72,
    84,  96,  112, 128, 144, 160, 180, 200, 220, 240, 264,
    288, 312, 336, 364, 392, 420, 448, 480, 512, 544};

typedef _Float16 half8 __attribute__((ext_vector_type(8)));
typedef float floatx4 __attribute__((ext_vector_type(4)));

// ---------------------------------------------------------------------------
// Kernel 1: per-block partial sufficient stats (unchanged).
// ---------------------------------------------------------------------------
template <bool ITER0, bool ATOMIC, int TILES>
__global__ __launch_bounds__(256, 1) void gmm_accum(
    const float* __restrict__ feat, const int* __restrict__ labels,
    const float* __restrict__ resp, float* __restrict__ outbuf) {
  __shared__ float fT[64 * 36];
  __shared__ float resp_lds[64 * 4];
  __shared__ int lab_lds[64];

  const int t = threadIdx.x;
  const int b = blockIdx.y;
  const int blk0 = blockIdx.x * (TILES * 64);

  const int wv = t >> 6;
  const int l = t & 63;
  const int sc = (t >> 4) & 3;
  const int p = t & 15;
  const int a0 = (p >> 2) * 8;
  const int b0 = (p & 3) * 8;

  float acc[8][8];
#pragma unroll
  for (int x = 0; x < 8; ++x)
#pragma unroll
    for (int y = 0; y < 8; ++y) acc[x][y] = 0.f;
  float sx[8] = {0, 0, 0, 0, 0, 0, 0, 0};
  float wacc = 0.f;

  const int cload = t >> 4;
  const int i4 = (t & 15) * 4;

  float4 pf0, pf1;
  float4 presp = make_float4(0, 0, 0, 0);
  int plab = 0;
  {
    const int n0 = blk0;
    pf0 = *(const float4*)(feat + ((size_t)b * CC + cload) * NN + n0 + i4);
    pf1 = *(const float4*)(feat + ((size_t)b * CC + cload + 16) * NN + n0 + i4);
    if (t < 64) {
      plab = labels[b * NN + n0 + t];
      if (!ITER0)
        presp = *(const float4*)(resp + ((size_t)b * NN + n0 + t) * 4);
    }
  }

  for (int tile = 0; tile < TILES; ++tile) {
    fT[(i4 + 0) * 36 + cload] = pf0.x;
    fT[(i4 + 1) * 36 + cload] = pf0.y;
    fT[(i4 + 2) * 36 + cload] = pf0.z;
    fT[(i4 + 3) * 36 + cload] = pf0.w;
    fT[(i4 + 0) * 36 + cload + 16] = pf1.x;
    fT[(i4 + 1) * 36 + cload + 16] = pf1.y;
    fT[(i4 + 2) * 36 + cload + 16] = pf1.z;
    fT[(i4 + 3) * 36 + cload + 16] = pf1.w;
    if (t < 64) {
      lab_lds[t] = plab;
      if (ITER0) {
        const int cmp = (blk0 + tile * 64 + t) & 3;
        resp_lds[t * 4 + 0] = (cmp == 0) ? 1.f : 0.f;
        resp_lds[t * 4 + 1] = (cmp == 1) ? 1.f : 0.f;
        resp_lds[t * 4 + 2] = (cmp == 2) ? 1.f : 0.f;
        resp_lds[t * 4 + 3] = (cmp == 3) ? 1.f : 0.f;
      } else {
        resp_lds[t * 4 + 0] = presp.x;
        resp_lds[t * 4 + 1] = presp.y;
        resp_lds[t * 4 + 2] = presp.z;
        resp_lds[t * 4 + 3] = presp.w;
      }
    }
    __syncthreads();
    if (tile < TILES - 1) {
      const int n0 = blk0 + (tile + 1) * 64;
      pf0 = *(const float4*)(feat + ((size_t)b * CC + cload) * NN + n0 + i4);
      pf1 =
          *(const float4*)(feat + ((size_t)b * CC + cload + 16) * NN + n0 + i4);
      if (t < 64) {
        plab = labels[b * NN + n0 + t];
        if (!ITER0)
          presp = *(const float4*)(resp + ((size_t)b * NN + n0 + t) * 4);
      }
    }

    unsigned long long m = __ballot(lab_lds[l] == wv);
    while (m) {
      const int i = __builtin_ctzll(m);
      m &= m - 1;
      const float rs = resp_lds[i * 4 + sc];
      const float4 ra0 = *(const float4*)&fT[i * 36 + a0];
      const float4 ra1 = *(const float4*)&fT[i * 36 + a0 + 4];
      const float4 rb0 = *(const float4*)&fT[i * 36 + b0];
      const float4 rb1 = *(const float4*)&fT[i * 36 + b0 + 4];
      const float ra[8] = {ra0.x, ra0.y, ra0.z, ra0.w,
                           ra1.x, ra1.y, ra1.z, ra1.w};
      const float rb[8] = {rb0.x, rb0.y, rb0.z, rb0.w,
                           rb1.x, rb1.y, rb1.z, rb1.w};
#pragma unroll
      for (int x = 0; x < 8; ++x) {
        const float v = rs * ra[x];
#pragma unroll
        for (int y = 0; y < 8; ++y) acc[x][y] = fmaf(v, rb[y], acc[x][y]);
      }
#pragma unroll
      for (int y = 0; y < 8; ++y) sx[y] = fmaf(rs, rb[y], sx[y]);
      wacc += rs;
    }
    __syncthreads();
  }

  if (ATOMIC) {
    float* sg = outbuf + ((size_t)(b * KK + wv) * SS + sc) * SSTRIDE;
#pragma unroll
    for (int x = 0; x < 8; ++x)
#pragma unroll
      for (int y = 0; y < 8; ++y)
        atomicAdd(sg + (a0 + x) * 32 + b0 + y, acc[x][y]);
    if (p < 4) {
#pragma unroll
      for (int y = 0; y < 8; ++y) atomicAdd(sg + 1024 + b0 + y, sx[y]);
    }
    if (p == 0) atomicAdd(sg + 1056, wacc);
  } else {
    const int nb = NN / (TILES * 64);
    float* sg = outbuf + ((size_t)(b * nb + blockIdx.x) * 16 + (wv * 4 + sc)) *
                             SSTRIDE;
#pragma unroll
    for (int x = 0; x < 8; ++x)
#pragma unroll
      for (int y = 0; y < 8; ++y) sg[(a0 + x) * 32 + b0 + y] = acc[x][y];
    if (p < 4) {
#pragma unroll
      for (int y = 0; y < 8; ++y) sg[1024 + b0 + y] = sx[y];
    }
    if (p == 0) sg[1056] = wacc;
  }
}

// ---------------------------------------------------------------------------
// Kernel 1b: reduce block-partials -> stats (unchanged).
// ---------------------------------------------------------------------------
__global__ __launch_bounds__(256) void gmm_reduce(const float* __restrict__ part,
                                                  float* __restrict__ stats,
                                                  int nb) {
  const int idx = blockIdx.x * 256 + threadIdx.x;
  if (idx >= NCOMP * 1057) return;
  const int comp = idx / 1057;
  const int cell = idx - comp * 1057;
  const int b = comp >> 4, cl = comp & 15;
  const float* src = part + ((size_t)(b * nb) * 16 + cl) * SSTRIDE + cell;
  const size_t stride = (size_t)16 * SSTRIDE;
  float s0 = 0.f, s1 = 0.f;
#pragma unroll 8
  for (int blk = 0; blk < nb; blk += 2) {
    s0 += src[(size_t)blk * stride];
    s1 += src[(size_t)(blk + 1) * stride];
  }
  stats[(size_t)comp * SSTRIDE + cell] = s0 + s1;
}

// ---------------------------------------------------------------------------
// Kernel 2 v2: params via register/shfl Cholesky (R14 diagnosis: old LDS
// in-place factorization serialized on unprovable LDS aliasing -> ~125K cyc
// critical path, 52us at 0.6% occupancy).  Lane i = row i of A in 32 regs,
// fully unrolled (static indices); shfl broadcasts replace LDS round-trips.
// X = inv(L) by column recurrence (lane c = column c; r<c zeros fall out).
// X -> LDS once; epilogue identical to R14 (proven).
// ---------------------------------------------------------------------------
__global__ __launch_bounds__(64) void gmm_params(const float* __restrict__ stats,
                                                 float* __restrict__ params) {
  __shared__ float Xl[32 * 33];
  __shared__ float mul[32];

  const int t = threadIdx.x;
  const int i = t & 31;  // row (Cholesky) / column (inversion); lanes 32-63 dup
  const int comp = blockIdx.x;
  const float* sg = stats + (size_t)comp * SSTRIDE;

  const float w = sg[1056];
  const float invw = 1.f / (w + EPS_);
  const float mu_i = sg[1024 + i] * invw;

  // cov row i in registers
  float a[32];
#pragma unroll
  for (int j4 = 0; j4 < 8; ++j4) {
    const float4 v = *(const float4*)(sg + i * 32 + 4 * j4);
    a[4 * j4 + 0] = v.x;
    a[4 * j4 + 1] = v.y;
    a[4 * j4 + 2] = v.z;
    a[4 * j4 + 3] = v.w;
  }
#pragma unroll
  for (int j = 0; j < 32; ++j) {
    const float muj = sg[1024 + j] * invw;  // uniform (s_load)
    float v = fmaf(a[j], invw, -mu_i * muj);
    v = (j == i) ? v + COVREG_ : v;
    a[j] = v;
  }

  // Cholesky, fully unrolled; lane i keeps row i of L in a[0..i]
  float ldet = 0.f;
  float rd[32];  // 1/L[j][j], uniform
#pragma unroll
  for (int j = 0; j < 32; ++j) {
    const float diag = __shfl(a[j], j);
    ldet += logf(diag);
    const float rinv = rsqrtf(diag);
    rd[j] = rinv;
    const float lij = a[j] * rinv;  // for i>=j; i==j gives sqrt(diag)
    a[j] = (i >= j) ? lij : a[j];
#pragma unroll
    for (int m = j + 1; m < 32; ++m) {
      const float Lmj = __shfl(lij, m);
      a[m] = (i >= m) ? fmaf(-lij, Lmj, a[m]) : a[m];
    }
  }

  // X = inv(L): lane c=i holds column c; recurrence over rows m.
  // X[m][c] = (d(m,c) - sum_{r<m} L[m][r]*X[r][c]) / L[m][m]; r<c zeros
  // emerge naturally (X[0][c]=0 for c>0, inductively).
  float x[32];
#pragma unroll
  for (int m = 0; m < 32; ++m) {
    float s = (m == i) ? 1.f : 0.f;
#pragma unroll
    for (int r = 0; r < m; ++r) {
      const float Lmr = __shfl(a[r], m);
      s = fmaf(-Lmr, x[r], s);
    }
    x[m] = s * rd[m];
  }

  // write X (column i) and mu to LDS for the proven epilogue
  if (t < 32) {
#pragma unroll
    for (int m = 0; m < 32; ++m) Xl[m * 33 + i] = x[m];
    mul[i] = mu_i;
  }
  __syncthreads();

  float* pg = params + (size_t)comp * PSTRIDE;
  for (int r = 0; r < 32; ++r) {
    const int L4 = 4 * ((r >> 2) + 1);
    if (t < L4) pg[XOFF_[r] + t] = (t <= r) ? Xl[r * 33 + t] : 0.f;
  }
  // fragment-major fp16 X
  {
    __half* xh = (__half*)(pg + 612);
#pragma unroll
    for (int th = 0; th < 2; ++th) {
      const int row = th * 16 + (t & 15);
      const int k0 = (t >> 4) * 8;
#pragma unroll
      for (int j = 0; j < 8; ++j) {
        const int k = k0 + j;
        const float v = (k <= row) ? Xl[row * 33 + k] : 0.f;
        xh[(th * 64 + t) * 8 + j] = __float2half(v);
      }
    }
  }
  if (t < 32) {
    float z = 0.f;
    for (int j = 0; j <= t; ++j) z += Xl[t * 33 + j] * mul[j];
    pg[576 + t] = z;
  }
  if (t == 0) {
    const int sib = comp & ~3;
    float wsum = 0.f;
    for (int s2 = 0; s2 < 4; ++s2)
      wsum += stats[(size_t)(sib + s2) * SSTRIDE + 1056];
    const float pi = (w + EPS_) / (wsum + SS * EPS_);
    pg[608] = logf(pi) - 0.5f * (CC * LOG2PI_C + ldet);
  }
}

// ---------------------------------------------------------------------------
// Kernel 3a v5: own-class E-step, MFMA core (unchanged from R14).
// ---------------------------------------------------------------------------
template <int TILES>
__global__ __launch_bounds__(256, 2) void gmm_estep_own4(
    const float* __restrict__ feat, const int* __restrict__ labels,
    const float* __restrict__ params, float* __restrict__ resp) {
  __shared__ float fT[64 * 36];
  __shared__ int4 xlds4[2048];  // 16 comps x 1024 halves = 32KB
  __shared__ float zlds[16 * 32];
  __shared__ float c0lds[16];
  __shared__ int lab_lds[64];

  const int t = threadIdx.x;
  const int b = blockIdx.y;
  const int blk0 = blockIdx.x * (TILES * 64);
  const int w = t >> 6;
  const int l = t & 63;
  const int row16 = l & 15;
  const int kg = l >> 4;

  for (int idx = t; idx < 2048; idx += 256) {
    const int c = idx >> 7, chunk = idx & 127;
    xlds4[idx] = *(const int4*)((const char*)(params +
                                              (size_t)(b * 16 + c) * PSTRIDE +
                                              612) +
                                chunk * 16);
  }
  for (int idx = t; idx < 16 * 32; idx += 256) {
    zlds[idx] =
        params[(size_t)(b * 16 + (idx >> 5)) * PSTRIDE + 576 + (idx & 31)];
  }
  if (t < 16) c0lds[t] = params[(size_t)(b * 16 + t) * PSTRIDE + 608];

  const _Float16* xl = (const _Float16*)xlds4;
  const int cload = t >> 4;
  const int i4 = (t & 15) * 4;
  const floatx4 zero4 = {0.f, 0.f, 0.f, 0.f};

  for (int tile = 0; tile < TILES; ++tile) {
    const int base = blk0 + tile * 64;
    {
      const float4 v0 =
          *(const float4*)(feat + ((size_t)b * CC + cload) * NN + base + i4);
      const float4 v1 = *(const float4*)(feat +
                                         ((size_t)b * CC + cload + 16) * NN +
                                         base + i4);
      fT[(i4 + 0) * 36 + cload] = v0.x;
      fT[(i4 + 1) * 36 + cload] = v0.y;
      fT[(i4 + 2) * 36 + cload] = v0.z;
      fT[(i4 + 3) * 36 + cload] = v0.w;
      fT[(i4 + 0) * 36 + cload + 16] = v1.x;
      fT[(i4 + 1) * 36 + cload + 16] = v1.y;
      fT[(i4 + 2) * 36 + cload + 16] = v1.z;
      fT[(i4 + 3) * 36 + cload + 16] = v1.w;
      if (t < 64) lab_lds[t] = labels[b * NN + base + t];
    }
    __syncthreads();

    const int eoff = (w * 16 + row16) * 36 + kg * 8;
    const float4 fv0 = *(const float4*)&fT[eoff];
    const float4 fv1 = *(const float4*)&fT[eoff + 4];
    half8 bfr;
    bfr[0] = (_Float16)fv0.x;
    bfr[1] = (_Float16)fv0.y;
    bfr[2] = (_Float16)fv0.z;
    bfr[3] = (_Float16)fv0.w;
    bfr[4] = (_Float16)fv1.x;
    bfr[5] = (_Float16)fv1.y;
    bfr[6] = (_Float16)fv1.z;
    bfr[7] = (_Float16)fv1.w;

    const int lab = lab_lds[w * 16 + row16];

    float lp0 = 0.f, lp1 = 0.f, lp2 = 0.f, lp3 = 0.f;
#pragma unroll
    for (int c = 0; c < 16; ++c) {
      const half8 a0 = *(const half8*)&xl[c * 1024 + (0 * 64 + l) * 8];
      const half8 a1 = *(const half8*)&xl[c * 1024 + (1 * 64 + l) * 8];
      floatx4 y0 =
          __builtin_amdgcn_mfma_f32_16x16x32_f16(a0, bfr, zero4, 0, 0, 0);
      floatx4 y1 =
          __builtin_amdgcn_mfma_f32_16x16x32_f16(a1, bfr, zero4, 0, 0, 0);
      const float4 zv0 = *(const float4*)&zlds[c * 32 + kg * 4];
      const float4 zv1 = *(const float4*)&zlds[c * 32 + 16 + kg * 4];
      float q = 0.f;
      {
        const float d0 = y0[0] - zv0.x;
        const float d1 = y0[1] - zv0.y;
        const float d2 = y0[2] - zv0.z;
        const float d3 = y0[3] - zv0.w;
        q = fmaf(d0, d0, q);
        q = fmaf(d1, d1, q);
        q = fmaf(d2, d2, q);
        q = fmaf(d3, d3, q);
        const float e0 = y1[0] - zv1.x;
        const float e1 = y1[1] - zv1.y;
        const float e2 = y1[2] - zv1.z;
        const float e3 = y1[3] - zv1.w;
        q = fmaf(e0, e0, q);
        q = fmaf(e1, e1, q);
        q = fmaf(e2, e2, q);
        q = fmaf(e3, e3, q);
      }
      q += __shfl_xor(q, 16);
      q += __shfl_xor(q, 32);
      const float lp = c0lds[c] - 0.5f * q;
      const bool own = (c >> 2) == lab;
      const int s = c & 3;
      lp0 = (own && s == 0) ? lp : lp0;
      lp1 = (own && s == 1) ? lp : lp1;
      lp2 = (own && s == 2) ? lp : lp2;
      lp3 = (own && s == 3) ? lp : lp3;
    }

    const float m = fmaxf(fmaxf(lp0, lp1), fmaxf(lp2, lp3));
    const float e0 = expf(lp0 - m), e1 = expf(lp1 - m);
    const float e2 = expf(lp2 - m), e3 = expf(lp3 - m);
    const float inv = 1.f / (e0 + e1 + e2 + e3);
    if (l < 16) {
      *(float4*)(resp + ((size_t)b * NN + base + w * 16 + l) * 4) =
          make_float4(e0 * inv, e1 * inv, e2 * inv, e3 * inv);
    }
    __syncthreads();
  }
}

// ---------------------------------------------------------------------------
// Kernel 3b v3: final E-step, MFMA core (unchanged from R14).
// ---------------------------------------------------------------------------
template <int TILES>
__global__ __launch_bounds__(256, 2) void gmm_estep_final4(
    const float* __restrict__ feat, const float* __restrict__ params,
    float* __restrict__ out) {
  __shared__ float fT[64 * 36];
  __shared__ int4 xlds4[2048];
  __shared__ float zlds[16 * 32];
  __shared__ float c0lds[16];

  const int t = threadIdx.x;
  const int b = blockIdx.y;
  const int blk0 = blockIdx.x * (TILES * 64);
  const int w = t >> 6;
  const int l = t & 63;
  const int row16 = l & 15;
  const int kg = l >> 4;

  for (int idx = t; idx < 2048; idx += 256) {
    const int c = idx >> 7, chunk = idx & 127;
    xlds4[idx] = *(const int4*)((const char*)(params +
                                              (size_t)(b * 16 + c) * PSTRIDE +
                                              612) +
                                chunk * 16);
  }
  for (int idx = t; idx < 16 * 32; idx += 256) {
    zlds[idx] =
        params[(size_t)(b * 16 + (idx >> 5)) * PSTRIDE + 576 + (idx & 31)];
  }
  if (t < 16) c0lds[t] = params[(size_t)(b * 16 + t) * PSTRIDE + 608];

  const _Float16* xl = (const _Float16*)xlds4;
  const int cload = t >> 4;
  const int i4 = (t & 15) * 4;
  const floatx4 zero4 = {0.f, 0.f, 0.f, 0.f};

  for (int tile = 0; tile < TILES; ++tile) {
    const int base = blk0 + tile * 64;
    {
      const float4 v0 =
          *(const float4*)(feat + ((size_t)b * CC + cload) * NN + base + i4);
      const float4 v1 = *(const float4*)(feat +
                                         ((size_t)b * CC + cload + 16) * NN +
                                         base + i4);
      fT[(i4 + 0) * 36 + cload] = v0.x;
      fT[(i4 + 1) * 36 + cload] = v0.y;
      fT[(i4 + 2) * 36 + cload] = v0.z;
      fT[(i4 + 3) * 36 + cload] = v0.w;
      fT[(i4 + 0) * 36 + cload + 16] = v1.x;
      fT[(i4 + 1) * 36 + cload + 16] = v1.y;
      fT[(i4 + 2) * 36 + cload + 16] = v1.z;
      fT[(i4 + 3) * 36 + cload + 16] = v1.w;
    }
    __syncthreads();

    const int eoff = (w * 16 + row16) * 36 + kg * 8;
    const float4 fv0 = *(const float4*)&fT[eoff];
    const float4 fv1 = *(const float4*)&fT[eoff + 4];
    half8 bfr;
    bfr[0] = (_Float16)fv0.x;
    bfr[1] = (_Float16)fv0.y;
    bfr[2] = (_Float16)fv0.z;
    bfr[3] = (_Float16)fv0.w;
    bfr[4] = (_Float16)fv1.x;
    bfr[5] = (_Float16)fv1.y;
    bfr[6] = (_Float16)fv1.z;
    bfr[7] = (_Float16)fv1.w;

    float lp[16];
#pragma unroll
    for (int c = 0; c < 16; ++c) {
      const half8 a0 = *(const half8*)&xl[c * 1024 + (0 * 64 + l) * 8];
      const half8 a1 = *(const half8*)&xl[c * 1024 + (1 * 64 + l) * 8];
      floatx4 y0 =
          __builtin_amdgcn_mfma_f32_16x16x32_f16(a0, bfr, zero4, 0, 0, 0);
      floatx4 y1 =
          __builtin_amdgcn_mfma_f32_16x16x32_f16(a1, bfr, zero4, 0, 0, 0);
      const float4 zv0 = *(const float4*)&zlds[c * 32 + kg * 4];
      const float4 zv1 = *(const float4*)&zlds[c * 32 + 16 + kg * 4];
      float q = 0.f;
      {
        const float d0 = y0[0] - zv0.x;
        const float d1 = y0[1] - zv0.y;
        const float d2 = y0[2] - zv0.z;
        const float d3 = y0[3] - zv0.w;
        q = fmaf(d0, d0, q);
        q = fmaf(d1, d1, q);
        q = fmaf(d2, d2, q);
        q = fmaf(d3, d3, q);
        const float e0 = y1[0] - zv1.x;
        const float e1 = y1[1] - zv1.y;
        const float e2 = y1[2] - zv1.z;
        const float e3 = y1[3] - zv1.w;
        q = fmaf(e0, e0, q);
        q = fmaf(e1, e1, q);
        q = fmaf(e2, e2, q);
        q = fmaf(e3, e3, q);
      }
      q += __shfl_xor(q, 16);
      q += __shfl_xor(q, 32);
      lp[c] = c0lds[c] - 0.5f * q;
    }

    float cll[4];
#pragma unroll
    for (int k = 0; k < 4; ++k) {
      const float m = fmaxf(fmaxf(lp[4 * k + 0], lp[4 * k + 1]),
                            fmaxf(lp[4 * k + 2], lp[4 * k + 3]));
      const float s = expf(lp[4 * k + 0] - m) + expf(lp[4 * k + 1] - m) +
                      expf(lp[4 * k + 2] - m) + expf(lp[4 * k + 3] - m);
      cll[k] = m + logf(s);
    }
    const float m = fmaxf(fmaxf(cll[0], cll[1]), fmaxf(cll[2], cll[3]));
    const float e0 = expf(cll[0] - m), e1 = expf(cll[1] - m);
    const float e2 = expf(cll[2] - m), e3 = expf(cll[3] - m);
    const float inv = 1.f / (e0 + e1 + e2 + e3);
    if (l < 16) {
      const int n = base + w * 16 + l;
      out[((size_t)b * KK + 0) * NN + n] = e0 * inv;
      out[((size_t)b * KK + 1) * NN + n] = e1 * inv;
      out[((size_t)b * KK + 2) * NN + n] = e2 * inv;
      out[((size_t)b * KK + 3) * NN + n] = e3 * inv;
    }
    __syncthreads();
  }
}

// ---------------------------------------------------------------------------
extern "C" void kernel_launch(void* const* d_in, const int* in_sizes, int n_in,
                              void* d_out, int out_size, void* d_ws,
                              size_t ws_size, hipStream_t stream) {
  const float* feat = (const float*)d_in[0];
  const int* labels = (const int*)d_in[1];
  float* out = (float*)d_out;

  float* stats = (float*)d_ws;
  float* params = stats + (size_t)NCOMP * SSTRIDE;
  float* resp_ws = params + (size_t)NCOMP * PSTRIDE;
  float* partials = resp_ws + (size_t)BB * NN * 4;

  constexpr int NB = 128;
  const size_t resp_end_b =
      ((size_t)NCOMP * SSTRIDE + (size_t)NCOMP * PSTRIDE + (size_t)BB * NN * 4) *
      sizeof(float);
  const size_t part_end_b =
      resp_end_b + (size_t)BB * NB * 16 * SSTRIDE * sizeof(float);
  const bool have_resp = ws_size >= resp_end_b;
  const bool have_part = ws_size >= part_end_b;
  float* resp = have_resp ? resp_ws : out;

  const int reduce_blocks = (NCOMP * 1057 + 255) / 256;

  for (int it = 0; it < 3; ++it) {
    if (have_part) {
      if (it == 0)
        gmm_accum<true, false, 8>
            <<<dim3(NB, BB), 256, 0, stream>>>(feat, labels, resp, partials);
      else
        gmm_accum<false, false, 8>
            <<<dim3(NB, BB), 256, 0, stream>>>(feat, labels, resp, partials);
      gmm_reduce<<<reduce_blocks, 256, 0, stream>>>(partials, stats, NB);
    } else {
      hipMemsetAsync(stats, 0, (size_t)NCOMP * SSTRIDE * sizeof(float), stream);
      if (it == 0)
        gmm_accum<true, true, 16>
            <<<dim3(64, BB), 256, 0, stream>>>(feat, labels, resp, stats);
      else
        gmm_accum<false, true, 16>
            <<<dim3(64, BB), 256, 0, stream>>>(feat, labels, resp, stats);
    }
    gmm_params<<<NCOMP, 64, 0, stream>>>(stats, params);
    if (it < 2)
      gmm_estep_own4<8><<<dim3(NN / 512, BB), 256, 0, stream>>>(feat, labels,
                                                                params, resp);
    else
      gmm_estep_final4<8><<<dim3(NN / 512, BB), 256, 0, stream>>>(feat, params,
                                                                  out);
  }
}

// Round 16
// 276.602 us; speedup vs baseline: 1.8350x; 1.2345x over previous
//
#include <hip/hip_runtime.h>
#include <hip/hip_fp16.h>
#include <math.h>

#define BB 4
#define CC 32
#define KK 4
#define SS 4
#define NN 65536

constexpr int NCOMP = 64;      // B*K*S
constexpr int SSTRIDE = 1088;  // stats: Sxx[0..1023], sx[1024..1055], w[1056]
// params per comp: X fp32 packed [0..575], z[576..607], c0[608],
//   X fp16 FRAGMENT-MAJOR [612..1123]
constexpr int PSTRIDE = 1128;
constexpr int NB = 128;  // accum blocks per b (partials path)
constexpr float EPS_ = 1e-6f;
constexpr float COVREG_ = 1e-4f;
constexpr float LOG2PI_C = 1.8378770664093453f;

__device__ constexpr int XOFF_[32] = {
    0,   4,   8,   12,  16,  24,  32,  40,  48,  60,  72,
    84,  96,  112, 128, 144, 160, 180, 200, 220, 240, 264,
    288, 312, 336, 364, 392, 420, 448, 480, 512, 544};

typedef _Float16 half8 __attribute__((ext_vector_type(8)));
typedef float floatx4 __attribute__((ext_vector_type(4)));

// ---------------------------------------------------------------------------
// Kernel 1 v2: sufficient stats via MFMA.  wave = class k; dense over all
// 4 (k-own) comps with masking folded into operands:
//   A = G^s (f*resp_s rows, aug row 32 = resp), B = H^k (f*mask cols,
//   aug col 32 = mask).  D[c][d]=Sxx, D[c][32]=sx, D[32][32]=w.
// 7 MFMAs/comp/chunk; acc[4][7] floatx4 = 112 VGPR (lb(256,2), no spill).
// fp16 f/resp quantization averages out over 16K elems (cov err ~1e-5).
// ---------------------------------------------------------------------------
template <bool ITER0>
__global__ __launch_bounds__(256, 2) void gmm_accum_mfma(
    const float* __restrict__ feat, const int* __restrict__ labels,
    const float* __restrict__ resp, float* __restrict__ partials) {
  __shared__ __align__(16) float fC[32 * 36];       // [channel][elem], pad 4
  __shared__ __align__(16) _Float16 respH[4][32];   // [s][elem]
  __shared__ __align__(16) _Float16 maskH[4][32];   // [k][elem]

  const int t = threadIdx.x;
  const int b = blockIdx.y;
  const int blk0 = blockIdx.x * 512;  // 16 chunks of 32 elems
  const int k = t >> 6;               // wave id == class
  const int l = t & 63;
  const int row16 = l & 15;
  const int kg = l >> 4;

  floatx4 acc[4][7];
#pragma unroll
  for (int s = 0; s < 4; ++s)
#pragma unroll
    for (int j = 0; j < 7; ++j) acc[s][j] = (floatx4){0.f, 0.f, 0.f, 0.f};

  const int cstage = t >> 3;      // channel 0..31
  const int n4 = (t & 7) * 4;     // elem sub-offset 0..28

  float4 pf;
  float4 presp = make_float4(0, 0, 0, 0);
  int plab = 0;
  // prefetch chunk 0
  pf = *(const float4*)(feat + ((size_t)b * CC + cstage) * NN + blk0 + n4);
  if (t < 32) {
    plab = labels[b * NN + blk0 + t];
    if (!ITER0) presp = *(const float4*)(resp + ((size_t)b * NN + blk0 + t) * 4);
  }

  const half8 hz = {0, 0, 0, 0, 0, 0, 0, 0};

  for (int chunk = 0; chunk < 16; ++chunk) {
    // commit staged chunk
    *(float4*)&fC[cstage * 36 + n4] = pf;
    if (t < 32) {
      if (ITER0) {
        const int cmp = (blk0 + chunk * 32 + t) & 3;
        respH[0][t] = (cmp == 0) ? (_Float16)1 : (_Float16)0;
        respH[1][t] = (cmp == 1) ? (_Float16)1 : (_Float16)0;
        respH[2][t] = (cmp == 2) ? (_Float16)1 : (_Float16)0;
        respH[3][t] = (cmp == 3) ? (_Float16)1 : (_Float16)0;
      } else {
        respH[0][t] = (_Float16)presp.x;
        respH[1][t] = (_Float16)presp.y;
        respH[2][t] = (_Float16)presp.z;
        respH[3][t] = (_Float16)presp.w;
      }
      maskH[0][t] = (plab == 0) ? (_Float16)1 : (_Float16)0;
      maskH[1][t] = (plab == 1) ? (_Float16)1 : (_Float16)0;
      maskH[2][t] = (plab == 2) ? (_Float16)1 : (_Float16)0;
      maskH[3][t] = (plab == 3) ? (_Float16)1 : (_Float16)0;
    }
    __syncthreads();

    if (chunk < 15) {  // prefetch next chunk
      const int n0n = blk0 + (chunk + 1) * 32;
      pf = *(const float4*)(feat + ((size_t)b * CC + cstage) * NN + n0n + n4);
      if (t < 32) {
        plab = labels[b * NN + n0n + t];
        if (!ITER0)
          presp = *(const float4*)(resp + ((size_t)b * NN + n0n + t) * 4);
      }
    }

    // f fragment (shared by A and B): channel rows / cols, k = elem
    const float4 fa0 = *(const float4*)&fC[row16 * 36 + kg * 8];
    const float4 fa1 = *(const float4*)&fC[row16 * 36 + kg * 8 + 4];
    const float4 fb0 = *(const float4*)&fC[(row16 + 16) * 36 + kg * 8];
    const float4 fb1 = *(const float4*)&fC[(row16 + 16) * 36 + kg * 8 + 4];
    half8 ff0, ff1;
    ff0[0] = (_Float16)fa0.x; ff0[1] = (_Float16)fa0.y;
    ff0[2] = (_Float16)fa0.z; ff0[3] = (_Float16)fa0.w;
    ff0[4] = (_Float16)fa1.x; ff0[5] = (_Float16)fa1.y;
    ff0[6] = (_Float16)fa1.z; ff0[7] = (_Float16)fa1.w;
    ff1[0] = (_Float16)fb0.x; ff1[1] = (_Float16)fb0.y;
    ff1[2] = (_Float16)fb0.z; ff1[3] = (_Float16)fb0.w;
    ff1[4] = (_Float16)fb1.x; ff1[5] = (_Float16)fb1.y;
    ff1[6] = (_Float16)fb1.z; ff1[7] = (_Float16)fb1.w;

    const half8 mh = *(const half8*)&maskH[k][kg * 8];
    const half8 H0 = ff0 * mh;
    const half8 H1 = ff1 * mh;
    const half8 agB = (row16 == 0) ? mh : hz;  // B col 32 = mask

#pragma unroll
    for (int s = 0; s < 4; ++s) {
      const half8 rh = *(const half8*)&respH[s][kg * 8];
      const half8 G0 = ff0 * rh;
      const half8 G1 = ff1 * rh;
      const half8 agA = (row16 == 0) ? rh : hz;  // A row 32 = resp
      acc[s][0] =
          __builtin_amdgcn_mfma_f32_16x16x32_f16(G0, H0, acc[s][0], 0, 0, 0);
      acc[s][1] =
          __builtin_amdgcn_mfma_f32_16x16x32_f16(G0, H1, acc[s][1], 0, 0, 0);
      acc[s][2] =
          __builtin_amdgcn_mfma_f32_16x16x32_f16(G1, H0, acc[s][2], 0, 0, 0);
      acc[s][3] =
          __builtin_amdgcn_mfma_f32_16x16x32_f16(G1, H1, acc[s][3], 0, 0, 0);
      acc[s][4] =
          __builtin_amdgcn_mfma_f32_16x16x32_f16(G0, agB, acc[s][4], 0, 0, 0);
      acc[s][5] =
          __builtin_amdgcn_mfma_f32_16x16x32_f16(G1, agB, acc[s][5], 0, 0, 0);
      acc[s][6] =
          __builtin_amdgcn_mfma_f32_16x16x32_f16(agA, agB, acc[s][6], 0, 0, 0);
    }
    __syncthreads();
  }

  // writeback: D layout col=l&15, row=kg*4+reg (m89-verified).
#pragma unroll
  for (int s = 0; s < 4; ++s) {
    float* sg = partials +
                ((size_t)(b * NB + blockIdx.x) * 16 + (k * 4 + s)) * SSTRIDE;
    const int dr = kg * 4;
#pragma unroll
    for (int r = 0; r < 4; ++r) {
      sg[(dr + r) * 32 + row16] = acc[s][0][r];
      sg[(dr + r) * 32 + 16 + row16] = acc[s][1][r];
      sg[(16 + dr + r) * 32 + row16] = acc[s][2][r];
      sg[(16 + dr + r) * 32 + 16 + row16] = acc[s][3][r];
    }
    if (row16 == 0) {
#pragma unroll
      for (int r = 0; r < 4; ++r) {
        sg[1024 + dr + r] = acc[s][4][r];
        sg[1024 + 16 + dr + r] = acc[s][5][r];
      }
    }
    if (l == 0) sg[1056] = acc[s][6][0];
  }
}

// ---------------------------------------------------------------------------
// Kernel 1 (old, ballot-based) — kept ONLY as the atomic fallback path.
// ---------------------------------------------------------------------------
template <bool ITER0, bool ATOMIC, int TILES>
__global__ __launch_bounds__(256, 1) void gmm_accum(
    const float* __restrict__ feat, const int* __restrict__ labels,
    const float* __restrict__ resp, float* __restrict__ outbuf) {
  __shared__ float fT[64 * 36];
  __shared__ float resp_lds[64 * 4];
  __shared__ int lab_lds[64];

  const int t = threadIdx.x;
  const int b = blockIdx.y;
  const int blk0 = blockIdx.x * (TILES * 64);

  const int wv = t >> 6;
  const int l = t & 63;
  const int sc = (t >> 4) & 3;
  const int p = t & 15;
  const int a0 = (p >> 2) * 8;
  const int b0 = (p & 3) * 8;

  float acc[8][8];
#pragma unroll
  for (int x = 0; x < 8; ++x)
#pragma unroll
    for (int y = 0; y < 8; ++y) acc[x][y] = 0.f;
  float sx[8] = {0, 0, 0, 0, 0, 0, 0, 0};
  float wacc = 0.f;

  const int cload = t >> 4;
  const int i4 = (t & 15) * 4;

  float4 pf0, pf1;
  float4 presp = make_float4(0, 0, 0, 0);
  int plab = 0;
  {
    const int n0 = blk0;
    pf0 = *(const float4*)(feat + ((size_t)b * CC + cload) * NN + n0 + i4);
    pf1 = *(const float4*)(feat + ((size_t)b * CC + cload + 16) * NN + n0 + i4);
    if (t < 64) {
      plab = labels[b * NN + n0 + t];
      if (!ITER0)
        presp = *(const float4*)(resp + ((size_t)b * NN + n0 + t) * 4);
    }
  }

  for (int tile = 0; tile < TILES; ++tile) {
    fT[(i4 + 0) * 36 + cload] = pf0.x;
    fT[(i4 + 1) * 36 + cload] = pf0.y;
    fT[(i4 + 2) * 36 + cload] = pf0.z;
    fT[(i4 + 3) * 36 + cload] = pf0.w;
    fT[(i4 + 0) * 36 + cload + 16] = pf1.x;
    fT[(i4 + 1) * 36 + cload + 16] = pf1.y;
    fT[(i4 + 2) * 36 + cload + 16] = pf1.z;
    fT[(i4 + 3) * 36 + cload + 16] = pf1.w;
    if (t < 64) {
      lab_lds[t] = plab;
      if (ITER0) {
        const int cmp = (blk0 + tile * 64 + t) & 3;
        resp_lds[t * 4 + 0] = (cmp == 0) ? 1.f : 0.f;
        resp_lds[t * 4 + 1] = (cmp == 1) ? 1.f : 0.f;
        resp_lds[t * 4 + 2] = (cmp == 2) ? 1.f : 0.f;
        resp_lds[t * 4 + 3] = (cmp == 3) ? 1.f : 0.f;
      } else {
        resp_lds[t * 4 + 0] = presp.x;
        resp_lds[t * 4 + 1] = presp.y;
        resp_lds[t * 4 + 2] = presp.z;
        resp_lds[t * 4 + 3] = presp.w;
      }
    }
    __syncthreads();
    if (tile < TILES - 1) {
      const int n0 = blk0 + (tile + 1) * 64;
      pf0 = *(const float4*)(feat + ((size_t)b * CC + cload) * NN + n0 + i4);
      pf1 =
          *(const float4*)(feat + ((size_t)b * CC + cload + 16) * NN + n0 + i4);
      if (t < 64) {
        plab = labels[b * NN + n0 + t];
        if (!ITER0)
          presp = *(const float4*)(resp + ((size_t)b * NN + n0 + t) * 4);
      }
    }

    unsigned long long m = __ballot(lab_lds[l] == wv);
    while (m) {
      const int i = __builtin_ctzll(m);
      m &= m - 1;
      const float rs = resp_lds[i * 4 + sc];
      const float4 ra0 = *(const float4*)&fT[i * 36 + a0];
      const float4 ra1 = *(const float4*)&fT[i * 36 + a0 + 4];
      const float4 rb0 = *(const float4*)&fT[i * 36 + b0];
      const float4 rb1 = *(const float4*)&fT[i * 36 + b0 + 4];
      const float ra[8] = {ra0.x, ra0.y, ra0.z, ra0.w,
                           ra1.x, ra1.y, ra1.z, ra1.w};
      const float rb[8] = {rb0.x, rb0.y, rb0.z, rb0.w,
                           rb1.x, rb1.y, rb1.z, rb1.w};
#pragma unroll
      for (int x = 0; x < 8; ++x) {
        const float v = rs * ra[x];
#pragma unroll
        for (int y = 0; y < 8; ++y) acc[x][y] = fmaf(v, rb[y], acc[x][y]);
      }
#pragma unroll
      for (int y = 0; y < 8; ++y) sx[y] = fmaf(rs, rb[y], sx[y]);
      wacc += rs;
    }
    __syncthreads();
  }

  if (ATOMIC) {
    float* sg = outbuf + ((size_t)(b * KK + wv) * SS + sc) * SSTRIDE;
#pragma unroll
    for (int x = 0; x < 8; ++x)
#pragma unroll
      for (int y = 0; y < 8; ++y)
        atomicAdd(sg + (a0 + x) * 32 + b0 + y, acc[x][y]);
    if (p < 4) {
#pragma unroll
      for (int y = 0; y < 8; ++y) atomicAdd(sg + 1024 + b0 + y, sx[y]);
    }
    if (p == 0) atomicAdd(sg + 1056, wacc);
  } else {
    const int nb = NN / (TILES * 64);
    float* sg = outbuf + ((size_t)(b * nb + blockIdx.x) * 16 + (wv * 4 + sc)) *
                             SSTRIDE;
#pragma unroll
    for (int x = 0; x < 8; ++x)
#pragma unroll
      for (int y = 0; y < 8; ++y) sg[(a0 + x) * 32 + b0 + y] = acc[x][y];
    if (p < 4) {
#pragma unroll
      for (int y = 0; y < 8; ++y) sg[1024 + b0 + y] = sx[y];
    }
    if (p == 0) sg[1056] = wacc;
  }
}

// ---------------------------------------------------------------------------
// Kernel 1b: reduce block-partials -> stats (unchanged).
// ---------------------------------------------------------------------------
__global__ __launch_bounds__(256) void gmm_reduce(const float* __restrict__ part,
                                                  float* __restrict__ stats,
                                                  int nb) {
  const int idx = blockIdx.x * 256 + threadIdx.x;
  if (idx >= NCOMP * 1057) return;
  const int comp = idx / 1057;
  const int cell = idx - comp * 1057;
  const int b = comp >> 4, cl = comp & 15;
  const float* src = part + ((size_t)(b * nb) * 16 + cl) * SSTRIDE + cell;
  const size_t stride = (size_t)16 * SSTRIDE;
  float s0 = 0.f, s1 = 0.f;
#pragma unroll 8
  for (int blk = 0; blk < nb; blk += 2) {
    s0 += src[(size_t)blk * stride];
    s1 += src[(size_t)(blk + 1) * stride];
  }
  stats[(size_t)comp * SSTRIDE + cell] = s0 + s1;
}

// ---------------------------------------------------------------------------
// Kernel 2 v2: params via register/shfl Cholesky (unchanged from R15).
// ---------------------------------------------------------------------------
__global__ __launch_bounds__(64) void gmm_params(const float* __restrict__ stats,
                                                 float* __restrict__ params) {
  __shared__ float Xl[32 * 33];
  __shared__ float mul[32];

  const int t = threadIdx.x;
  const int i = t & 31;
  const int comp = blockIdx.x;
  const float* sg = stats + (size_t)comp * SSTRIDE;

  const float w = sg[1056];
  const float invw = 1.f / (w + EPS_);
  const float mu_i = sg[1024 + i] * invw;

  float a[32];
#pragma unroll
  for (int j4 = 0; j4 < 8; ++j4) {
    const float4 v = *(const float4*)(sg + i * 32 + 4 * j4);
    a[4 * j4 + 0] = v.x;
    a[4 * j4 + 1] = v.y;
    a[4 * j4 + 2] = v.z;
    a[4 * j4 + 3] = v.w;
  }
#pragma unroll
  for (int j = 0; j < 32; ++j) {
    const float muj = sg[1024 + j] * invw;
    float v = fmaf(a[j], invw, -mu_i * muj);
    v = (j == i) ? v + COVREG_ : v;
    a[j] = v;
  }

  float ldet = 0.f;
  float rd[32];
#pragma unroll
  for (int j = 0; j < 32; ++j) {
    const float diag = __shfl(a[j], j);
    ldet += logf(diag);
    const float rinv = rsqrtf(diag);
    rd[j] = rinv;
    const float lij = a[j] * rinv;
    a[j] = (i >= j) ? lij : a[j];
#pragma unroll
    for (int m = j + 1; m < 32; ++m) {
      const float Lmj = __shfl(lij, m);
      a[m] = (i >= m) ? fmaf(-lij, Lmj, a[m]) : a[m];
    }
  }

  float x[32];
#pragma unroll
  for (int m = 0; m < 32; ++m) {
    float s = (m == i) ? 1.f : 0.f;
#pragma unroll
    for (int r = 0; r < m; ++r) {
      const float Lmr = __shfl(a[r], m);
      s = fmaf(-Lmr, x[r], s);
    }
    x[m] = s * rd[m];
  }

  if (t < 32) {
#pragma unroll
    for (int m = 0; m < 32; ++m) Xl[m * 33 + i] = x[m];
    mul[i] = mu_i;
  }
  __syncthreads();

  float* pg = params + (size_t)comp * PSTRIDE;
  for (int r = 0; r < 32; ++r) {
    const int L4 = 4 * ((r >> 2) + 1);
    if (t < L4) pg[XOFF_[r] + t] = (t <= r) ? Xl[r * 33 + t] : 0.f;
  }
  {
    __half* xh = (__half*)(pg + 612);
#pragma unroll
    for (int th = 0; th < 2; ++th) {
      const int row = th * 16 + (t & 15);
      const int k0 = (t >> 4) * 8;
#pragma unroll
      for (int j = 0; j < 8; ++j) {
        const int k = k0 + j;
        const float v = (k <= row) ? Xl[row * 33 + k] : 0.f;
        xh[(th * 64 + t) * 8 + j] = __float2half(v);
      }
    }
  }
  if (t < 32) {
    float z = 0.f;
    for (int j = 0; j <= t; ++j) z += Xl[t * 33 + j] * mul[j];
    pg[576 + t] = z;
  }
  if (t == 0) {
    const int sib = comp & ~3;
    float wsum = 0.f;
    for (int s2 = 0; s2 < 4; ++s2)
      wsum += stats[(size_t)(sib + s2) * SSTRIDE + 1056];
    const float pi = (w + EPS_) / (wsum + SS * EPS_);
    pg[608] = logf(pi) - 0.5f * (CC * LOG2PI_C + ldet);
  }
}

// ---------------------------------------------------------------------------
// Kernel 3a v5: own-class E-step, MFMA core (unchanged from R14).
// ---------------------------------------------------------------------------
template <int TILES>
__global__ __launch_bounds__(256, 2) void gmm_estep_own4(
    const float* __restrict__ feat, const int* __restrict__ labels,
    const float* __restrict__ params, float* __restrict__ resp) {
  __shared__ float fT[64 * 36];
  __shared__ int4 xlds4[2048];
  __shared__ float zlds[16 * 32];
  __shared__ float c0lds[16];
  __shared__ int lab_lds[64];

  const int t = threadIdx.x;
  const int b = blockIdx.y;
  const int blk0 = blockIdx.x * (TILES * 64);
  const int w = t >> 6;
  const int l = t & 63;
  const int row16 = l & 15;
  const int kg = l >> 4;

  for (int idx = t; idx < 2048; idx += 256) {
    const int c = idx >> 7, chunk = idx & 127;
    xlds4[idx] = *(const int4*)((const char*)(params +
                                              (size_t)(b * 16 + c) * PSTRIDE +
                                              612) +
                                chunk * 16);
  }
  for (int idx = t; idx < 16 * 32; idx += 256) {
    zlds[idx] =
        params[(size_t)(b * 16 + (idx >> 5)) * PSTRIDE + 576 + (idx & 31)];
  }
  if (t < 16) c0lds[t] = params[(size_t)(b * 16 + t) * PSTRIDE + 608];

  const _Float16* xl = (const _Float16*)xlds4;
  const int cload = t >> 4;
  const int i4 = (t & 15) * 4;
  const floatx4 zero4 = {0.f, 0.f, 0.f, 0.f};

  for (int tile = 0; tile < TILES; ++tile) {
    const int base = blk0 + tile * 64;
    {
      const float4 v0 =
          *(const float4*)(feat + ((size_t)b * CC + cload) * NN + base + i4);
      const float4 v1 = *(const float4*)(feat +
                                         ((size_t)b * CC + cload + 16) * NN +
                                         base + i4);
      fT[(i4 + 0) * 36 + cload] = v0.x;
      fT[(i4 + 1) * 36 + cload] = v0.y;
      fT[(i4 + 2) * 36 + cload] = v0.z;
      fT[(i4 + 3) * 36 + cload] = v0.w;
      fT[(i4 + 0) * 36 + cload + 16] = v1.x;
      fT[(i4 + 1) * 36 + cload + 16] = v1.y;
      fT[(i4 + 2) * 36 + cload + 16] = v1.z;
      fT[(i4 + 3) * 36 + cload + 16] = v1.w;
      if (t < 64) lab_lds[t] = labels[b * NN + base + t];
    }
    __syncthreads();

    const int eoff = (w * 16 + row16) * 36 + kg * 8;
    const float4 fv0 = *(const float4*)&fT[eoff];
    const float4 fv1 = *(const float4*)&fT[eoff + 4];
    half8 bfr;
    bfr[0] = (_Float16)fv0.x;
    bfr[1] = (_Float16)fv0.y;
    bfr[2] = (_Float16)fv0.z;
    bfr[3] = (_Float16)fv0.w;
    bfr[4] = (_Float16)fv1.x;
    bfr[5] = (_Float16)fv1.y;
    bfr[6] = (_Float16)fv1.z;
    bfr[7] = (_Float16)fv1.w;

    const int lab = lab_lds[w * 16 + row16];

    float lp0 = 0.f, lp1 = 0.f, lp2 = 0.f, lp3 = 0.f;
#pragma unroll
    for (int c = 0; c < 16; ++c) {
      const half8 a0 = *(const half8*)&xl[c * 1024 + (0 * 64 + l) * 8];
      const half8 a1 = *(const half8*)&xl[c * 1024 + (1 * 64 + l) * 8];
      floatx4 y0 =
          __builtin_amdgcn_mfma_f32_16x16x32_f16(a0, bfr, zero4, 0, 0, 0);
      floatx4 y1 =
          __builtin_amdgcn_mfma_f32_16x16x32_f16(a1, bfr, zero4, 0, 0, 0);
      const float4 zv0 = *(const float4*)&zlds[c * 32 + kg * 4];
      const float4 zv1 = *(const float4*)&zlds[c * 32 + 16 + kg * 4];
      float q = 0.f;
      {
        const float d0 = y0[0] - zv0.x;
        const float d1 = y0[1] - zv0.y;
        const float d2 = y0[2] - zv0.z;
        const float d3 = y0[3] - zv0.w;
        q = fmaf(d0, d0, q);
        q = fmaf(d1, d1, q);
        q = fmaf(d2, d2, q);
        q = fmaf(d3, d3, q);
        const float e0 = y1[0] - zv1.x;
        const float e1 = y1[1] - zv1.y;
        const float e2 = y1[2] - zv1.z;
        const float e3 = y1[3] - zv1.w;
        q = fmaf(e0, e0, q);
        q = fmaf(e1, e1, q);
        q = fmaf(e2, e2, q);
        q = fmaf(e3, e3, q);
      }
      q += __shfl_xor(q, 16);
      q += __shfl_xor(q, 32);
      const float lp = c0lds[c] - 0.5f * q;
      const bool own = (c >> 2) == lab;
      const int s = c & 3;
      lp0 = (own && s == 0) ? lp : lp0;
      lp1 = (own && s == 1) ? lp : lp1;
      lp2 = (own && s == 2) ? lp : lp2;
      lp3 = (own && s == 3) ? lp : lp3;
    }

    const float m = fmaxf(fmaxf(lp0, lp1), fmaxf(lp2, lp3));
    const float e0 = expf(lp0 - m), e1 = expf(lp1 - m);
    const float e2 = expf(lp2 - m), e3 = expf(lp3 - m);
    const float inv = 1.f / (e0 + e1 + e2 + e3);
    if (l < 16) {
      *(float4*)(resp + ((size_t)b * NN + base + w * 16 + l) * 4) =
          make_float4(e0 * inv, e1 * inv, e2 * inv, e3 * inv);
    }
    __syncthreads();
  }
}

// ---------------------------------------------------------------------------
// Kernel 3b v3: final E-step, MFMA core (unchanged from R14).
// ---------------------------------------------------------------------------
template <int TILES>
__global__ __launch_bounds__(256, 2) void gmm_estep_final4(
    const float* __restrict__ feat, const float* __restrict__ params,
    float* __restrict__ out) {
  __shared__ float fT[64 * 36];
  __shared__ int4 xlds4[2048];
  __shared__ float zlds[16 * 32];
  __shared__ float c0lds[16];

  const int t = threadIdx.x;
  const int b = blockIdx.y;
  const int blk0 = blockIdx.x * (TILES * 64);
  const int w = t >> 6;
  const int l = t & 63;
  const int row16 = l & 15;
  const int kg = l >> 4;

  for (int idx = t; idx < 2048; idx += 256) {
    const int c = idx >> 7, chunk = idx & 127;
    xlds4[idx] = *(const int4*)((const char*)(params +
                                              (size_t)(b * 16 + c) * PSTRIDE +
                                              612) +
                                chunk * 16);
  }
  for (int idx = t; idx < 16 * 32; idx += 256) {
    zlds[idx] =
        params[(size_t)(b * 16 + (idx >> 5)) * PSTRIDE + 576 + (idx & 31)];
  }
  if (t < 16) c0lds[t] = params[(size_t)(b * 16 + t) * PSTRIDE + 608];

  const _Float16* xl = (const _Float16*)xlds4;
  const int cload = t >> 4;
  const int i4 = (t & 15) * 4;
  const floatx4 zero4 = {0.f, 0.f, 0.f, 0.f};

  for (int tile = 0; tile < TILES; ++tile) {
    const int base = blk0 + tile * 64;
    {
      const float4 v0 =
          *(const float4*)(feat + ((size_t)b * CC + cload) * NN + base + i4);
      const float4 v1 = *(const float4*)(feat +
                                         ((size_t)b * CC + cload + 16) * NN +
                                         base + i4);
      fT[(i4 + 0) * 36 + cload] = v0.x;
      fT[(i4 + 1) * 36 + cload] = v0.y;
      fT[(i4 + 2) * 36 + cload] = v0.z;
      fT[(i4 + 3) * 36 + cload] = v0.w;
      fT[(i4 + 0) * 36 + cload + 16] = v1.x;
      fT[(i4 + 1) * 36 + cload + 16] = v1.y;
      fT[(i4 + 2) * 36 + cload + 16] = v1.z;
      fT[(i4 + 3) * 36 + cload + 16] = v1.w;
    }
    __syncthreads();

    const int eoff = (w * 16 + row16) * 36 + kg * 8;
    const float4 fv0 = *(const float4*)&fT[eoff];
    const float4 fv1 = *(const float4*)&fT[eoff + 4];
    half8 bfr;
    bfr[0] = (_Float16)fv0.x;
    bfr[1] = (_Float16)fv0.y;
    bfr[2] = (_Float16)fv0.z;
    bfr[3] = (_Float16)fv0.w;
    bfr[4] = (_Float16)fv1.x;
    bfr[5] = (_Float16)fv1.y;
    bfr[6] = (_Float16)fv1.z;
    bfr[7] = (_Float16)fv1.w;

    float lp[16];
#pragma unroll
    for (int c = 0; c < 16; ++c) {
      const half8 a0 = *(const half8*)&xl[c * 1024 + (0 * 64 + l) * 8];
      const half8 a1 = *(const half8*)&xl[c * 1024 + (1 * 64 + l) * 8];
      floatx4 y0 =
          __builtin_amdgcn_mfma_f32_16x16x32_f16(a0, bfr, zero4, 0, 0, 0);
      floatx4 y1 =
          __builtin_amdgcn_mfma_f32_16x16x32_f16(a1, bfr, zero4, 0, 0, 0);
      const float4 zv0 = *(const float4*)&zlds[c * 32 + kg * 4];
      const float4 zv1 = *(const float4*)&zlds[c * 32 + 16 + kg * 4];
      float q = 0.f;
      {
        const float d0 = y0[0] - zv0.x;
        const float d1 = y0[1] - zv0.y;
        const float d2 = y0[2] - zv0.z;
        const float d3 = y0[3] - zv0.w;
        q = fmaf(d0, d0, q);
        q = fmaf(d1, d1, q);
        q = fmaf(d2, d2, q);
        q = fmaf(d3, d3, q);
        const float e0 = y1[0] - zv1.x;
        const float e1 = y1[1] - zv1.y;
        const float e2 = y1[2] - zv1.z;
        const float e3 = y1[3] - zv1.w;
        q = fmaf(e0, e0, q);
        q = fmaf(e1, e1, q);
        q = fmaf(e2, e2, q);
        q = fmaf(e3, e3, q);
      }
      q += __shfl_xor(q, 16);
      q += __shfl_xor(q, 32);
      lp[c] = c0lds[c] - 0.5f * q;
    }

    float cll[4];
#pragma unroll
    for (int k = 0; k < 4; ++k) {
      const float m = fmaxf(fmaxf(lp[4 * k + 0], lp[4 * k + 1]),
                            fmaxf(lp[4 * k + 2], lp[4 * k + 3]));
      const float s = expf(lp[4 * k + 0] - m) + expf(lp[4 * k + 1] - m) +
                      expf(lp[4 * k + 2] - m) + expf(lp[4 * k + 3] - m);
      cll[k] = m + logf(s);
    }
    const float m = fmaxf(fmaxf(cll[0], cll[1]), fmaxf(cll[2], cll[3]));
    const float e0 = expf(cll[0] - m), e1 = expf(cll[1] - m);
    const float e2 = expf(cll[2] - m), e3 = expf(cll[3] - m);
    const float inv = 1.f / (e0 + e1 + e2 + e3);
    if (l < 16) {
      const int n = base + w * 16 + l;
      out[((size_t)b * KK + 0) * NN + n] = e0 * inv;
      out[((size_t)b * KK + 1) * NN + n] = e1 * inv;
      out[((size_t)b * KK + 2) * NN + n] = e2 * inv;
      out[((size_t)b * KK + 3) * NN + n] = e3 * inv;
    }
    __syncthreads();
  }
}

// ---------------------------------------------------------------------------
extern "C" void kernel_launch(void* const* d_in, const int* in_sizes, int n_in,
                              void* d_out, int out_size, void* d_ws,
                              size_t ws_size, hipStream_t stream) {
  const float* feat = (const float*)d_in[0];
  const int* labels = (const int*)d_in[1];
  float* out = (float*)d_out;

  float* stats = (float*)d_ws;
  float* params = stats + (size_t)NCOMP * SSTRIDE;
  float* resp_ws = params + (size_t)NCOMP * PSTRIDE;
  float* partials = resp_ws + (size_t)BB * NN * 4;

  const size_t resp_end_b =
      ((size_t)NCOMP * SSTRIDE + (size_t)NCOMP * PSTRIDE + (size_t)BB * NN * 4) *
      sizeof(float);
  const size_t part_end_b =
      resp_end_b + (size_t)BB * NB * 16 * SSTRIDE * sizeof(float);
  const bool have_resp = ws_size >= resp_end_b;
  const bool have_part = ws_size >= part_end_b;
  float* resp = have_resp ? resp_ws : out;

  const int reduce_blocks = (NCOMP * 1057 + 255) / 256;

  for (int it = 0; it < 3; ++it) {
    if (have_part) {
      if (it == 0)
        gmm_accum_mfma<true>
            <<<dim3(NB, BB), 256, 0, stream>>>(feat, labels, resp, partials);
      else
        gmm_accum_mfma<false>
            <<<dim3(NB, BB), 256, 0, stream>>>(feat, labels, resp, partials);
      gmm_reduce<<<reduce_blocks, 256, 0, stream>>>(partials, stats, NB);
    } else {
      hipMemsetAsync(stats, 0, (size_t)NCOMP * SSTRIDE * sizeof(float), stream);
      if (it == 0)
        gmm_accum<true, true, 16>
            <<<dim3(64, BB), 256, 0, stream>>>(feat, labels, resp, stats);
      else
        gmm_accum<false, true, 16>
            <<<dim3(64, BB), 256, 0, stream>>>(feat, labels, resp, stats);
    }
    gmm_params<<<NCOMP, 64, 0, stream>>>(stats, params);
    if (it < 2)
      gmm_estep_own4<8><<<dim3(NN / 512, BB), 256, 0, stream>>>(feat, labels,
                                                                params, resp);
    else
      gmm_estep_final4<8><<<dim3(NN / 512, BB), 256, 0, stream>>>(feat, params,
                                                                  out);
  }
}